// Round 3
// baseline (802.167 us; speedup 1.0000x reference)
//
#include <hip/hip_runtime.h>
#include <hip/hip_bf16.h>
#include <cstdint>
#include <cstddef>

#define B_ 2
#define N_ 384
#define D_ 128
#define NN (N_*N_)                  // 147456
#define BN (B_*N_)                  // 768
#define EDGE_ELEMS (B_*NN*D_)       // 37748736
#define NODE_ELEMS (BN*D_)          // 98304

typedef short bh8 __attribute__((ext_vector_type(8)));
typedef float f32x4 __attribute__((ext_vector_type(4)));

__device__ __forceinline__ f32x4 mfma_bf16(bh8 a, bh8 b, f32x4 c){
  return __builtin_amdgcn_mfma_f32_16x16x32_bf16(a, b, c, 0, 0, 0);
}
__device__ __forceinline__ unsigned short f2bf(float f){
  unsigned u = __float_as_uint(f);
  return (unsigned short)((u + 0x7fffu + ((u >> 16) & 1u)) >> 16);
}
__device__ __forceinline__ unsigned f2bf_pk(float a, float b){   // packed cvt: lo=a, hi=b
  __hip_bfloat162 h = __float22bfloat162_rn(make_float2(a, b));
  return *(unsigned*)&h;
}
__device__ __forceinline__ float bf2f(unsigned short h){
  return __uint_as_float(((unsigned)h) << 16);
}
__device__ __forceinline__ float geluf(float x){        // exact (node path)
  return 0.5f * x * (1.0f + erff(x * 0.70710678118654752f));
}
__device__ __forceinline__ float gelu_fast(float x){    // tanh approx via hw exp
  float x2 = x * x;
  float t  = __fmaf_rn(0.044715f * x, x2, x);
  float e  = __expf(1.5957691216057308f * t);
  float r  = __builtin_amdgcn_rcpf(e + 1.0f);
  return x - x * r;
}
__device__ __forceinline__ f32x4 zero4(){ f32x4 z = {0.f,0.f,0.f,0.f}; return z; }

// ---- DPP reductions (VALU pipe) ----
__device__ __forceinline__ float red16_add(float x){
  x += __int_as_float(__builtin_amdgcn_update_dpp(0, __float_as_int(x), 0xB1, 0xF, 0xF, true));  // quad_perm [1,0,3,2]
  x += __int_as_float(__builtin_amdgcn_update_dpp(0, __float_as_int(x), 0x4E, 0xF, 0xF, true));  // quad_perm [2,3,0,1]
  x += __int_as_float(__builtin_amdgcn_update_dpp(0, __float_as_int(x), 0x141, 0xF, 0xF, true)); // row_half_mirror
  x += __int_as_float(__builtin_amdgcn_update_dpp(0, __float_as_int(x), 0x140, 0xF, 0xF, true)); // row_mirror
  return x;
}
__device__ __forceinline__ float red4_add(float x){
  x += __int_as_float(__builtin_amdgcn_update_dpp(0, __float_as_int(x), 0xB1, 0xF, 0xF, true));
  x += __int_as_float(__builtin_amdgcn_update_dpp(0, __float_as_int(x), 0x4E, 0xF, 0xF, true));
  return x;
}
// XOR chunk swizzle: logical (row m, short-pos p in 0..255) -> physical short index.
// Only the low 3 bits of the 16B-chunk index are XORed -> valid for lo (K/edge2) and hi (stage) halves.
__device__ __forceinline__ int swz(int m, int p){
  return ((((p >> 3) ^ (m & 7)) << 3) | (p & 7));
}
// channel-pairing permutation: position p holds channel phi(p) (rotate-right of low 5 bits);
// storage position of channel c is sigma(c) = rotate-left of low 5 bits.
__device__ __forceinline__ int PHIDX(int x){   // x < 128
  return (x & ~31) | ((x & 1) << 4) | ((x & 31) >> 1);
}

// ------- merged prep: y<5 weight bf16-transpose (phi-permuted K), y==5 node qkv GEMV -------
__global__ void kprep(const float* wqkv_e, const float* e0_we, const float* e0_w1,
                      const float* e1_w1, const float* e1_w2,
                      const float* node, const float* wqkv_n,
                      unsigned short* WqkvT, unsigned short* WeT, unsigned short* W1T,
                      unsigned short* E1W1T, unsigned short* E1W2T,
                      float* qkvn){
  int m = blockIdx.y;
  int tid = threadIdx.x;
  if (m < 5){
    const float* src; unsigned short* dst; int K, Nn;
    if (m == 0){ src = wqkv_e; dst = WqkvT; K = 128; Nn = 512; }
    else if (m == 1){ src = e0_we; dst = WeT;   K = 256; Nn = 128; }
    else if (m == 2){ src = e0_w1; dst = W1T;   K = 128; Nn = 128; }
    else if (m == 3){ src = e1_w1; dst = E1W1T; K = 128; Nn = 256; }
    else            { src = e1_w2; dst = E1W2T; K = 256; Nn = 128; }
    int idx = blockIdx.x * 384 + tid;
    if (idx < K * Nn){
      int n = idx / K, k = idx % K;
      int ksrc = (m >= 2) ? ((k & ~127) | PHIDX(k & 127)) : k;  // bake channel-pair perm into K
      dst[idx] = f2bf(src[ksrc * Nn + n]);
    }
  } else {
    int row = blockIdx.x;
    __shared__ float sn[128];
    if (tid < 128) sn[tid] = node[row * 128 + tid];
    __syncthreads();
    float acc = 0.f;
    #pragma unroll 8
    for (int k = 0; k < 128; ++k) acc += sn[k] * wqkv_n[k * 384 + tid];
    qkvn[row * 384 + tid] = acc;
  }
}

// ---------------- fused: edge fp32 -> bf16 + meanJ (contiguous row pass) ----------------
__global__ void kprepA(const float* __restrict__ edge, unsigned short* __restrict__ E16,
                       float* __restrict__ meanJ){
  __shared__ float red[8][128];
  int bi = blockIdx.x; int tid = threadIdx.x;
  const float4* src = (const float4*)(edge + (size_t)bi * N_ * D_);
  uint2* gdst = (uint2*)E16 + (size_t)bi * (N_ * D_ / 4);
  float ps0 = 0.f, ps1 = 0.f, ps2 = 0.f, ps3 = 0.f;
  #pragma unroll 4
  for (int k = 0; k < 48; ++k){
    int idx = k * 256 + tid;
    float4 v = src[idx];
    uint2 o;
    o.x = f2bf_pk(v.x, v.y);
    o.y = f2bf_pk(v.z, v.w);
    gdst[idx] = o;
    ps0 += v.x; ps1 += v.y; ps2 += v.z; ps3 += v.w;
  }
  int g = tid >> 5, d0 = (tid & 31) * 4;
  red[g][d0] = ps0; red[g][d0 + 1] = ps1; red[g][d0 + 2] = ps2; red[g][d0 + 3] = ps3;
  __syncthreads();
  if (tid < 128){
    float s = 0.f;
    #pragma unroll
    for (int gg = 0; gg < 8; ++gg) s += red[gg][tid];
    meanJ[bi * 128 + tid] = s * (1.0f / N_);
  }
}

// ---- merged: y==0 attention (2 heads/wave, prefetch), y==1 meanI column pass ----
__global__ __launch_bounds__(256, 2) void kattnI(
    const unsigned short* __restrict__ E16, const unsigned short* __restrict__ WqkvT,
    const float* __restrict__ qkvn, float* __restrict__ attn,
    float* __restrict__ meanI){
  __shared__ float red[16][128];
  int tid = threadIdx.x;
  if (blockIdx.y == 1){
    int bj = blockIdx.x; int b = bj / N_, j = bj % N_;
    int ig = tid >> 4, dsub = tid & 15;
    float acc[8];
    #pragma unroll
    for (int e = 0; e < 8; ++e) acc[e] = 0.f;
    #pragma unroll 4
    for (int i = ig; i < N_; i += 16){
      const unsigned short* p = E16 + ((size_t)(b * N_ + i) * N_ + j) * D_ + dsub * 8;
      uint4 u = *(const uint4*)p;
      acc[0] += bf2f((unsigned short)(u.x & 0xffff)); acc[1] += bf2f((unsigned short)(u.x >> 16));
      acc[2] += bf2f((unsigned short)(u.y & 0xffff)); acc[3] += bf2f((unsigned short)(u.y >> 16));
      acc[4] += bf2f((unsigned short)(u.z & 0xffff)); acc[5] += bf2f((unsigned short)(u.z >> 16));
      acc[6] += bf2f((unsigned short)(u.w & 0xffff)); acc[7] += bf2f((unsigned short)(u.w >> 16));
    }
    #pragma unroll
    for (int e = 0; e < 8; ++e) red[ig][dsub * 8 + e] = acc[e];
    __syncthreads();
    if (tid < 128){
      float s = 0.f;
      #pragma unroll
      for (int gg = 0; gg < 16; ++gg) s += red[gg][tid];
      meanI[bj * 128 + tid] = s * (1.0f / N_);
    }
    return;
  }
  int bi = blockIdx.x; int b = bi / N_;
  int w = tid >> 6, lane = tid & 63, quad = lane >> 4, c16 = lane & 15;
  const float scale = 0.08838834764831845f;   // 1/sqrt(128)
  const unsigned short* Abase = E16 + (size_t)bi * N_ * D_;

  bh8 bf[2][4][4];
  #pragma unroll
  for (int s = 0; s < 2; ++s){
    int h = w + s * 4;
    #pragma unroll
    for (int u = 0; u < 4; ++u)
      #pragma unroll
      for (int ks = 0; ks < 4; ++ks){
        int col = h * 64 + u * 16 + c16;
        bf[s][u][ks] = *(const bh8*)(WqkvT + col * 128 + ks * 32 + quad * 8);
      }
  }
  float qv[2];
  #pragma unroll
  for (int s = 0; s < 2; ++s) qv[s] = qkvn[bi * 384 + (w + s * 4) * 48 + c16];

  float m_run[2] = {-1e30f, -1e30f}, l_run[2] = {0.f, 0.f}, o[2] = {0.f, 0.f};
  bh8 af[4];
  #pragma unroll
  for (int ks = 0; ks < 4; ++ks)
    af[ks] = *(const bh8*)(Abase + (size_t)c16 * D_ + ks * 32 + quad * 8);

  for (int jt = 0; jt < 24; ++jt){
    int jn = (jt + 1 < 24) ? jt + 1 : 0;
    bh8 afn[4];
    #pragma unroll
    for (int ks = 0; ks < 4; ++ks)
      afn[ks] = *(const bh8*)(Abase + (size_t)(jn * 16 + c16) * D_ + ks * 32 + quad * 8);
    float knv[2][4], vnv[2][4];
    const float* kvb = qkvn + ((size_t)b * N_ + jt * 16 + quad * 4) * 384;
    #pragma unroll
    for (int s = 0; s < 2; ++s)
      #pragma unroll
      for (int r = 0; r < 4; ++r){
        knv[s][r] = kvb[r * 384 + (w + s * 4) * 48 + 16 + c16];
        vnv[s][r] = kvb[r * 384 + (w + s * 4) * 48 + 32 + c16];
      }
    f32x4 EQ[2], EK[2], EV[2], EM[2];
    #pragma unroll
    for (int s = 0; s < 2; ++s){ EQ[s] = zero4(); EK[s] = zero4(); EV[s] = zero4(); EM[s] = zero4(); }
    #pragma unroll
    for (int ks = 0; ks < 4; ++ks)
      #pragma unroll
      for (int s = 0; s < 2; ++s){
        EQ[s] = mfma_bf16(af[ks], bf[s][0][ks], EQ[s]);
        EK[s] = mfma_bf16(af[ks], bf[s][1][ks], EK[s]);
        EV[s] = mfma_bf16(af[ks], bf[s][2][ks], EV[s]);
        EM[s] = mfma_bf16(af[ks], bf[s][3][ks], EM[s]);
      }
    #pragma unroll
    for (int s = 0; s < 2; ++s){
      float dots[4], vv[4];
      #pragma unroll
      for (int r = 0; r < 4; ++r){
        float t1 = (qv[s] + EQ[s][r]) * (knv[s][r] + EK[s][r]);
        dots[r] = red16_add(t1) * scale;
        vv[r] = vnv[s][r] * EM[s][r] + EV[s][r];
      }
      float tmax = fmaxf(fmaxf(dots[0], dots[1]), fmaxf(dots[2], dots[3]));
      tmax = fmaxf(tmax, __shfl_xor(tmax, 16));
      tmax = fmaxf(tmax, __shfl_xor(tmax, 32));
      float mnew = fmaxf(m_run[s], tmax);
      float al = __expf(m_run[s] - mnew);
      float p0 = __expf(dots[0] - mnew), p1 = __expf(dots[1] - mnew);
      float p2 = __expf(dots[2] - mnew), p3 = __expf(dots[3] - mnew);
      float lt = p0 + p1 + p2 + p3;
      lt += __shfl_xor(lt, 16); lt += __shfl_xor(lt, 32);
      l_run[s] = l_run[s] * al + lt;
      m_run[s] = mnew;
      o[s] = o[s] * al + p0 * vv[0] + p1 * vv[1] + p2 * vv[2] + p3 * vv[3];
    }
    #pragma unroll
    for (int ks = 0; ks < 4; ++ks) af[ks] = afn[ks];
  }
  #pragma unroll
  for (int s = 0; s < 2; ++s){
    float oo = o[s];
    oo += __shfl_xor(oo, 16); oo += __shfl_xor(oo, 32);
    oo /= l_run[s];
    if (quad == 0) attn[(size_t)bi * D_ + (w + s * 4) * 16 + c16] = oo;
  }
}

// -------- merged node path: lin0+LN0+MLP+LN1 then rowAdd/colAdd GEMVs --------
__global__ void knodeadd(const float* __restrict__ node, const float* __restrict__ attn,
                         const float* lin0_w, const float* lin0_b,
                         const float* g0, const float* bb0,
                         const float* w1, const float* w2, const float* b2,
                         const float* g1, const float* bb1,
                         const float* __restrict__ meanJ, const float* __restrict__ meanI,
                         const float* ws, const float* bs, const float* wt, const float* bt,
                         const float* wer, const float* wec, const float* be,
                         float* __restrict__ xOut,
                         float* __restrict__ rowAdd, float* __restrict__ colAdd){
  int row = blockIdx.x; int tid = threadIdx.x;
  __shared__ float sa[128], sx[128], sh[256], rb[8], sx2[128], smJ[128], smI[128];
  if (tid < 128){
    sa[tid] = attn[row * 128 + tid];
    smJ[tid] = meanJ[row * 128 + tid];
    smI[tid] = meanI[row * 128 + tid];
  }
  __syncthreads();
  float y = 0.f, x0 = 0.f;
  if (tid < 128){
    float acc = lin0_b[tid];
    #pragma unroll 8
    for (int k = 0; k < 128; ++k) acc += sa[k] * lin0_w[k * 128 + tid];
    y = acc + node[row * 128 + tid];
  }
  { float sv = (tid < 128) ? y : 0.f, sq = (tid < 128) ? y * y : 0.f;
    sv = red16_add(sv); sq = red16_add(sq);
    sv += __shfl_xor(sv, 16); sq += __shfl_xor(sq, 16);
    sv += __shfl_xor(sv, 32); sq += __shfl_xor(sq, 32);
    if ((tid & 63) == 0){ rb[tid >> 6] = sv; rb[4 + (tid >> 6)] = sq; } }
  __syncthreads();
  float mean = (rb[0] + rb[1] + rb[2] + rb[3]) * (1.f / 128.f);
  float var  = (rb[4] + rb[5] + rb[6] + rb[7]) * (1.f / 128.f) - mean * mean;
  float rstd = rsqrtf(var + 1e-5f);
  if (tid < 128){ x0 = (y - mean) * rstd * g0[tid] + bb0[tid]; sx[tid] = x0; }
  __syncthreads();
  { float acc = 0.f;
    #pragma unroll 8
    for (int k = 0; k < 128; ++k) acc += sx[k] * w1[k * 256 + tid];
    sh[tid] = geluf(acc); }
  __syncthreads();
  float y2 = 0.f;
  if (tid < 128){
    float acc = b2[tid];
    #pragma unroll 8
    for (int e = 0; e < 256; ++e) acc += sh[e] * w2[e * 128 + tid];
    y2 = acc + x0;
  }
  __syncthreads();
  { float sv = (tid < 128) ? y2 : 0.f, sq = (tid < 128) ? y2 * y2 : 0.f;
    sv = red16_add(sv); sq = red16_add(sq);
    sv += __shfl_xor(sv, 16); sq += __shfl_xor(sq, 16);
    sv += __shfl_xor(sv, 32); sq += __shfl_xor(sq, 32);
    if ((tid & 63) == 0){ rb[tid >> 6] = sv; rb[4 + (tid >> 6)] = sq; } }
  __syncthreads();
  mean = (rb[0] + rb[1] + rb[2] + rb[3]) * (1.f / 128.f);
  var  = (rb[4] + rb[5] + rb[6] + rb[7]) * (1.f / 128.f) - mean * mean;
  rstd = rsqrtf(var + 1e-5f);
  if (tid < 128){
    float xv = (y2 - mean) * rstd * g1[tid] + bb1[tid];
    xOut[row * 128 + tid] = xv;
    sx2[tid] = xv;
  }
  __syncthreads();
  if (tid < 128){
    int d = tid;
    float s1 = bs[d], s3 = 0.f;
    #pragma unroll 8
    for (int k = 0; k < 128; ++k){
      s1 += sx2[k] * ws[k * 128 + d];
      s3 += smJ[k] * wer[k * 128 + d];
    }
    rowAdd[row * 128 + d] = s1 + s3 + be[d];
  } else {
    int d = tid - 128;
    float s2 = bt[d], s4 = 0.f;
    #pragma unroll 8
    for (int k = 0; k < 128; ++k){
      s2 += sx2[k] * wt[k * 128 + d];
      s4 += smI[k] * wec[k * 128 + d];
    }
    colAdd[row * 128 + d] = s2 + s4;
  }
}

// -- fused edge pipeline v7: 256 thr, single 32 KiB LDS buffer -> 5 blocks/CU.
//    sT role aliased into sA hi columns; LN scratch aliased into rows 0..9 hi.
//    Channel-pair permutation sigma (rotl5): u32 LDS writes, float2 full-line stores;
//    phi baked into W1T/E1W1T/E1W2T K-order by kprep.
__global__ __launch_bounds__(256, 5) void kedge4(
    const unsigned short* __restrict__ E16, const unsigned short* __restrict__ WeT,
    const unsigned short* __restrict__ W1T, const unsigned short* __restrict__ E1W1T,
    const unsigned short* __restrict__ E1W2T,
    const float* __restrict__ rowAdd, const float* __restrict__ colAdd,
    const float* __restrict__ b1, const float* __restrict__ eg0, const float* __restrict__ eb0,
    const float* __restrict__ e1b2, const float* __restrict__ eg1, const float* __restrict__ eb1,
    float* __restrict__ eOut){
  __shared__ unsigned short sA[64][256];   // lo (p<128): K0-127 / edge2; hi (p>=128): K128-255 / stage buf
#define HIFV(i) (((float*)&sA[0][0])[ (((i) >> 6) << 7) + 64 + ((i) & 63) ])  // hi-half float alias
  int tid = threadIdx.x;
  int w = tid >> 6, lane = tid & 63, quad = lane >> 4, c16 = lane & 15;
  int R0 = blockIdx.x * 64;
  int b = R0 / NN; int rem = R0 % NN; int i = rem / N_; int j0 = rem % N_;

  // ---- prefetch G1 weights ----
  bh8 wb1[2][8];
  #pragma unroll
  for (int t = 0; t < 2; ++t)
    #pragma unroll
    for (int ks = 0; ks < 8; ++ks){
      int col = w * 32 + t * 16 + c16;
      wb1[t][ks] = *(const bh8*)(WeT + (size_t)col * 256 + ks * 32 + quad * 8);
    }

  // ---- stage A = [edge(b,i,j0+m,:) | edge(b,j0+m,i,:)] bf16, 64x256, chunk-XOR ----
  #pragma unroll
  for (int it = 0; it < 8; ++it){
    int cid = it * 256 + tid;
    int rrow = cid >> 5;
    int chunk = cid & 31;
    int kc = chunk * 8;
    const unsigned short* sp;
    if (kc < 128) sp = E16 + ((size_t)(b * N_ + i) * N_ + (j0 + rrow)) * D_ + kc;
    else          sp = E16 + ((size_t)(b * N_ + j0 + rrow) * N_ + i) * D_ + (kc - 128);
    *(float4*)&sA[rrow][(chunk ^ (rrow & 7)) << 3] = *(const float4*)sp;
  }
  __syncthreads();                                         // B1: staged

  // ---- G1 k-loop: A(64x256) @ WeT^T -> cols [32w,32w+32) ----
  f32x4 acc1[2][4];
  #pragma unroll
  for (int t = 0; t < 2; ++t) for (int ms = 0; ms < 4; ++ms) acc1[t][ms] = zero4();
  #pragma unroll
  for (int ks = 0; ks < 8; ++ks){
    bh8 af[4];
    #pragma unroll
    for (int ms = 0; ms < 4; ++ms){
      int row = ms * 16 + c16;
      af[ms] = *(const bh8*)&sA[row][swz(row, ks * 32 + quad * 8)];
    }
    #pragma unroll
    for (int t = 0; t < 2; ++t)
      #pragma unroll
      for (int ms = 0; ms < 4; ++ms)
        acc1[t][ms] = mfma_bf16(af[ms], wb1[t][ks], acc1[t][ms]);
  }
  // addends (short live range; latency hidden by B1.5 wait)
  float rAv[2], ca[2][16];
  #pragma unroll
  for (int t = 0; t < 2; ++t){
    rAv[t] = rowAdd[(b * N_ + i) * D_ + w * 32 + t * 16 + c16];
    #pragma unroll
    for (int ms = 0; ms < 4; ++ms)
      #pragma unroll
      for (int r = 0; r < 4; ++r)
        ca[t][ms * 4 + r] = colAdd[(size_t)(b * N_ + j0 + ms * 16 + quad * 4 + r) * D_
                                   + w * 32 + t * 16 + c16];
  }
  __syncthreads();                                         // B1.5: all hi-K reads done

  // ---- gelu1 -> hi (paired u32 at position sigma) ----
  #pragma unroll
  for (int ms = 0; ms < 4; ++ms)
    #pragma unroll
    for (int r = 0; r < 4; ++r){
      int m = ms * 16 + quad * 4 + r;
      float v0 = gelu_fast(acc1[0][ms][r] + rAv[0] + ca[0][ms * 4 + r]);
      float v1 = gelu_fast(acc1[1][ms][r] + rAv[1] + ca[1][ms * 4 + r]);
      *(unsigned*)&sA[m][swz(m, 128 + w * 32 + c16 * 2)] = f2bf_pk(v0, v1);
    }
  __syncthreads();                                         // B2: gelu1 ready

  // ---- G2: gelu1 @ W1T^T (phi-K) + b1 + raw edge residual ----
  bh8 wb2[2][4];
  #pragma unroll
  for (int t = 0; t < 2; ++t)
    #pragma unroll
    for (int ks = 0; ks < 4; ++ks){
      int col = w * 32 + t * 16 + c16;
      wb2[t][ks] = *(const bh8*)(W1T + (size_t)col * 128 + ks * 32 + quad * 8);
    }
  f32x4 acc2[2][4];
  #pragma unroll
  for (int t = 0; t < 2; ++t) for (int ms = 0; ms < 4; ++ms) acc2[t][ms] = zero4();
  #pragma unroll
  for (int ks = 0; ks < 4; ++ks){
    bh8 af[4];
    #pragma unroll
    for (int ms = 0; ms < 4; ++ms){
      int row = ms * 16 + c16;
      af[ms] = *(const bh8*)&sA[row][swz(row, 128 + ks * 32 + quad * 8)];
    }
    #pragma unroll
    for (int t = 0; t < 2; ++t)
      #pragma unroll
      for (int ms = 0; ms < 4; ++ms)
        acc2[t][ms] = mfma_bf16(af[ms], wb2[t][ks], acc2[t][ms]);
  }
  float b1v[2], g0v[2], b0v[2];
  #pragma unroll
  for (int t = 0; t < 2; ++t){
    int c = w * 32 + t * 16 + c16;
    b1v[t] = b1[c]; g0v[t] = eg0[c]; b0v[t] = eb0[c];
  }
  __syncthreads();                                         // B3a: gelu1 reads done (lr aliases hi)
  // ---- residual + LN0 partials (DPP) -> lr ----
  #pragma unroll
  for (int ms = 0; ms < 4; ++ms)
    #pragma unroll
    for (int r = 0; r < 4; ++r){
      int m = ms * 16 + quad * 4 + r;
      float s = 0.f, q = 0.f;
      #pragma unroll
      for (int t = 0; t < 2; ++t){
        float v = acc2[t][ms][r] + b1v[t] + bf2f(sA[m][swz(m, w * 32 + t * 16 + c16)]);
        acc2[t][ms][r] = v; s += v; q += v * v;
      }
      s = red16_add(s); q = red16_add(q);
      if (c16 == 0){ HIFV(w * 64 + m) = s; HIFV(256 + w * 64 + m) = q; }
    }
  __syncthreads();                                         // B3b: lr ready
  {                                                        // wave w -> stats rows [16w,16w+16)
    int src = lane & 3, mrow = w * 16 + (lane >> 2);
    float sp = HIFV(src * 64 + mrow), qp = HIFV(256 + src * 64 + mrow);
    sp = red4_add(sp); qp = red4_add(qp);
    if (src == 0){
      float mean = sp * (1.f / 128.f);
      float var  = qp * (1.f / 128.f) - mean * mean;
      HIFV(512 + 2 * mrow) = mean;
      HIFV(513 + 2 * mrow) = rsqrtf(var + 1e-5f);
    }
  }
  __syncthreads();                                         // B4a: stats ready
  // ---- LN0 finalize -> edge2 bf16 into lo (paired u32 at position sigma) ----
  #pragma unroll
  for (int ms = 0; ms < 4; ++ms)
    #pragma unroll
    for (int r = 0; r < 4; ++r){
      int m = ms * 16 + quad * 4 + r;
      float2 st = *(float2*)&HIFV(512 + 2 * m);
      float e0 = (acc2[0][ms][r] - st.x) * st.y * g0v[0] + b0v[0];
      float e1 = (acc2[1][ms][r] - st.x) * st.y * g0v[1] + b0v[1];
      *(unsigned*)&sA[m][swz(m, w * 32 + c16 * 2)] = f2bf_pk(e0, e1);
    }
  __syncthreads();                                         // B4b: edge2 ready

  // ---- G3/G4 two-phase over K=256 (hi = gelu3 stage buffer) ----
  f32x4 acc4[2][4];
  #pragma unroll
  for (int t = 0; t < 2; ++t) for (int ms = 0; ms < 4; ++ms) acc4[t][ms] = zero4();
  #pragma unroll
  for (int p = 0; p < 2; ++p){
    bh8 wb3[2][4];
    #pragma unroll
    for (int t = 0; t < 2; ++t)
      #pragma unroll
      for (int ks = 0; ks < 4; ++ks){
        int col = p * 128 + w * 32 + t * 16 + c16;
        wb3[t][ks] = *(const bh8*)(E1W1T + (size_t)col * 128 + ks * 32 + quad * 8);
      }
    f32x4 acc3[2][4];
    #pragma unroll
    for (int t = 0; t < 2; ++t) for (int ms = 0; ms < 4; ++ms) acc3[t][ms] = zero4();
    #pragma unroll
    for (int ks = 0; ks < 4; ++ks){
      bh8 af[4];
      #pragma unroll
      for (int ms = 0; ms < 4; ++ms){
        int row = ms * 16 + c16;
        af[ms] = *(const bh8*)&sA[row][swz(row, ks * 32 + quad * 8)];
      }
      #pragma unroll
      for (int t = 0; t < 2; ++t)
        #pragma unroll
        for (int ms = 0; ms < 4; ++ms)
          acc3[t][ms] = mfma_bf16(af[ms], wb3[t][ks], acc3[t][ms]);
    }
    #pragma unroll
    for (int ms = 0; ms < 4; ++ms)
      #pragma unroll
      for (int r = 0; r < 4; ++r){
        int m = ms * 16 + quad * 4 + r;
        float v0 = gelu_fast(acc3[0][ms][r]);
        float v1 = gelu_fast(acc3[1][ms][r]);
        *(unsigned*)&sA[m][swz(m, 128 + w * 32 + c16 * 2)] = f2bf_pk(v0, v1);
      }
    __syncthreads();                                       // B5: gelu3 phase p ready
    bh8 wb4[2][4];
    #pragma unroll
    for (int t = 0; t < 2; ++t)
      #pragma unroll
      for (int k2 = 0; k2 < 4; ++k2){
        int pcol = w * 32 + c16 * 2 + t;                   // paired output column
        wb4[t][k2] = *(const bh8*)(E1W2T + (size_t)pcol * 256 + p * 128 + k2 * 32 + quad * 8);
      }
    #pragma unroll
    for (int k2 = 0; k2 < 4; ++k2){
      bh8 af[4];
      #pragma unroll
      for (int ms = 0; ms < 4; ++ms){
        int row = ms * 16 + c16;
        af[ms] = *(const bh8*)&sA[row][swz(row, 128 + k2 * 32 + quad * 8)];
      }
      #pragma unroll
      for (int t = 0; t < 2; ++t)
        #pragma unroll
        for (int ms = 0; ms < 4; ++ms)
          acc4[t][ms] = mfma_bf16(af[ms], wb4[t][k2], acc4[t][ms]);
    }
    __syncthreads();                                       // B6: hi reads done
  }

  // ---- G4 epilogue: + b2 + edge2 residual -> LN1 (DPP) -> full-line store ----
  float b2v[2], g1v[2], bb1v[2]; int slv[2];
  #pragma unroll
  for (int t = 0; t < 2; ++t){
    int pcol = w * 32 + c16 * 2 + t;
    b2v[t] = e1b2[pcol]; g1v[t] = eg1[pcol]; bb1v[t] = eb1[pcol];
    int lo5 = c16 * 2 + t;
    slv[t] = w * 32 + (((lo5 & 15) << 1) | (lo5 >> 4));    // sigma(pcol): edge2 storage position
  }
  #pragma unroll
  for (int ms = 0; ms < 4; ++ms)
    #pragma unroll
    for (int r = 0; r < 4; ++r){
      int m = ms * 16 + quad * 4 + r;
      float s = 0.f, q = 0.f;
      #pragma unroll
      for (int t = 0; t < 2; ++t){
        float v = acc4[t][ms][r] + b2v[t] + bf2f(sA[m][swz(m, slv[t])]);
        acc4[t][ms][r] = v; s += v; q += v * v;
      }
      s = red16_add(s); q = red16_add(q);
      if (c16 == 0){ HIFV(w * 64 + m) = s; HIFV(256 + w * 64 + m) = q; }
    }
  __syncthreads();                                         // B9: lr ready
  {
    int src = lane & 3, mrow = w * 16 + (lane >> 2);
    float sp = HIFV(src * 64 + mrow), qp = HIFV(256 + src * 64 + mrow);
    sp = red4_add(sp); qp = red4_add(qp);
    if (src == 0){
      float mean = sp * (1.f / 128.f);
      float var  = qp * (1.f / 128.f) - mean * mean;
      HIFV(512 + 2 * mrow) = mean;
      HIFV(513 + 2 * mrow) = rsqrtf(var + 1e-5f);
    }
  }
  __syncthreads();                                         // B10: stats ready
  float* outBase = eOut + ((size_t)(b * N_ + i) * N_ + j0) * D_;
  #pragma unroll
  for (int ms = 0; ms < 4; ++ms)
    #pragma unroll
    for (int r = 0; r < 4; ++r){
      int m = ms * 16 + quad * 4 + r;
      float2 st = *(float2*)&HIFV(512 + 2 * m);
      float2 ov;
      ov.x = (acc4[0][ms][r] - st.x) * st.y * g1v[0] + bb1v[0];
      ov.y = (acc4[1][ms][r] - st.x) * st.y * g1v[1] + bb1v[1];
      *(float2*)&outBase[(size_t)m * D_ + w * 32 + c16 * 2] = ov;   // 128B line per row per instr
    }
#undef HIFV
}

extern "C" void kernel_launch(void* const* d_in, const int* in_sizes, int n_in,
                              void* d_out, int out_size, void* d_ws, size_t ws_size,
                              hipStream_t stream){
  const float* node   = (const float*)d_in[0];
  const float* edge   = (const float*)d_in[1];
  const float* wqkv_n = (const float*)d_in[3];
  const float* wqkv_e = (const float*)d_in[4];
  const float* lin0_w = (const float*)d_in[5];
  const float* lin0_b = (const float*)d_in[6];
  const float* ln0_g  = (const float*)d_in[7];
  const float* ln0_b  = (const float*)d_in[8];
  const float* ln1_g  = (const float*)d_in[9];
  const float* ln1_b  = (const float*)d_in[10];
  const float* nmlp_w1= (const float*)d_in[11];
  const float* nmlp_w2= (const float*)d_in[12];
  const float* nmlp_b2= (const float*)d_in[13];
  const float* e0_we  = (const float*)d_in[14];
  const float* e0_be  = (const float*)d_in[15];
  const float* e0_ws  = (const float*)d_in[16];
  const float* e0_bs  = (const float*)d_in[17];
  const float* e0_wt  = (const float*)d_in[18];
  const float* e0_bt  = (const float*)d_in[19];
  const float* e0_wer = (const float*)d_in[20];
  const float* e0_wec = (const float*)d_in[21];
  const float* e0_w1  = (const float*)d_in[22];
  const float* e0_b1  = (const float*)d_in[23];
  const float* e1_w1  = (const float*)d_in[24];
  const float* e1_w2  = (const float*)d_in[25];
  const float* e1_b2  = (const float*)d_in[26];
  const float* eln0_g = (const float*)d_in[27];
  const float* eln0_b = (const float*)d_in[28];
  const float* eln1_g = (const float*)d_in[29];
  const float* eln1_b = (const float*)d_in[30];

  unsigned short* E16   = (unsigned short*)d_ws;
  unsigned short* WqkvT = E16 + (size_t)EDGE_ELEMS;
  unsigned short* WeT   = WqkvT + 65536;
  unsigned short* W1T   = WeT + 32768;
  unsigned short* E1W1T = W1T + 16384;
  unsigned short* E1W2T = E1W1T + 32768;
  float* fbase  = (float*)(E1W2T + 32768);
  float* qkvn   = fbase;
  float* attn   = qkvn + (size_t)BN * 384;
  float* meanJ  = attn + NODE_ELEMS;
  float* meanI  = meanJ + NODE_ELEMS;
  float* rowAdd = meanI + NODE_ELEMS;
  float* colAdd = rowAdd + NODE_ELEMS;

  float* xOut = (float*)d_out;
  float* eOut = xOut + NODE_ELEMS;

  kprep<<<dim3(BN, 6), 384, 0, stream>>>(wqkv_e, e0_we, e0_w1, e1_w1, e1_w2,
                                         node, wqkv_n,
                                         WqkvT, WeT, W1T, E1W1T, E1W2T, qkvn);
  kprepA<<<BN, 256, 0, stream>>>(edge, E16, meanJ);
  kattnI<<<dim3(BN, 2), 256, 0, stream>>>(E16, WqkvT, qkvn, attn, meanI);
  knodeadd<<<BN, 256, 0, stream>>>(node, attn, lin0_w, lin0_b, ln0_g, ln0_b,
                                   nmlp_w1, nmlp_w2, nmlp_b2, ln1_g, ln1_b,
                                   meanJ, meanI, e0_ws, e0_bs, e0_wt, e0_bt,
                                   e0_wer, e0_wec, e0_be,
                                   xOut, rowAdd, colAdd);
  kedge4<<<NN * B_ / 64, 256, 0, stream>>>(E16, WeT, W1T, E1W1T, E1W2T,
                                           rowAdd, colAdd, e0_b1,
                                           eln0_g, eln0_b, e1_b2, eln1_g, eln1_b,
                                           eOut);
}

// Round 4
// 657.079 us; speedup vs baseline: 1.2208x; 1.2208x over previous
//
#include <hip/hip_runtime.h>
#include <hip/hip_bf16.h>
#include <cstdint>
#include <cstddef>

#define B_ 2
#define N_ 384
#define D_ 128
#define NN (N_*N_)                  // 147456
#define BN (B_*N_)                  // 768
#define EDGE_ELEMS (B_*NN*D_)       // 37748736
#define NODE_ELEMS (BN*D_)          // 98304

typedef short bh8 __attribute__((ext_vector_type(8)));
typedef float f32x4 __attribute__((ext_vector_type(4)));

__device__ __forceinline__ f32x4 mfma_bf16(bh8 a, bh8 b, f32x4 c){
  return __builtin_amdgcn_mfma_f32_16x16x32_bf16(a, b, c, 0, 0, 0);
}
__device__ __forceinline__ unsigned short f2bf(float f){
  unsigned u = __float_as_uint(f);
  return (unsigned short)((u + 0x7fffu + ((u >> 16) & 1u)) >> 16);
}
__device__ __forceinline__ unsigned f2bf_pk(float a, float b){   // packed cvt: lo=a, hi=b
  __hip_bfloat162 h = __float22bfloat162_rn(make_float2(a, b));
  return *(unsigned*)&h;
}
__device__ __forceinline__ float bf2f(unsigned short h){
  return __uint_as_float(((unsigned)h) << 16);
}
__device__ __forceinline__ float geluf(float x){        // exact (node path)
  return 0.5f * x * (1.0f + erff(x * 0.70710678118654752f));
}
__device__ __forceinline__ float gelu_fast(float x){    // tanh approx via hw exp
  float x2 = x * x;
  float t  = __fmaf_rn(0.044715f * x, x2, x);
  float e  = __expf(1.5957691216057308f * t);
  float r  = __builtin_amdgcn_rcpf(e + 1.0f);
  return x - x * r;
}
__device__ __forceinline__ f32x4 zero4(){ f32x4 z = {0.f,0.f,0.f,0.f}; return z; }

// ---- DPP reductions (VALU pipe) ----
__device__ __forceinline__ float red16_add(float x){
  x += __int_as_float(__builtin_amdgcn_update_dpp(0, __float_as_int(x), 0xB1, 0xF, 0xF, true));  // quad_perm [1,0,3,2]
  x += __int_as_float(__builtin_amdgcn_update_dpp(0, __float_as_int(x), 0x4E, 0xF, 0xF, true));  // quad_perm [2,3,0,1]
  x += __int_as_float(__builtin_amdgcn_update_dpp(0, __float_as_int(x), 0x141, 0xF, 0xF, true)); // row_half_mirror
  x += __int_as_float(__builtin_amdgcn_update_dpp(0, __float_as_int(x), 0x140, 0xF, 0xF, true)); // row_mirror
  return x;
}
__device__ __forceinline__ float red4_add(float x){
  x += __int_as_float(__builtin_amdgcn_update_dpp(0, __float_as_int(x), 0xB1, 0xF, 0xF, true));
  x += __int_as_float(__builtin_amdgcn_update_dpp(0, __float_as_int(x), 0x4E, 0xF, 0xF, true));
  return x;
}
// XOR chunk swizzle: logical (row m, short-pos p in 0..255) -> physical short index.
// Only the low 3 bits of the 16B-chunk index are XORed -> valid for lo (K/edge2) and hi (stage) halves.
__device__ __forceinline__ int swz(int m, int p){
  return ((((p >> 3) ^ (m & 7)) << 3) | (p & 7));
}
// channel-pairing permutation: position p holds channel phi(p) (rotate-right of low 5 bits);
// storage position of channel c is sigma(c) = rotate-left of low 5 bits.
__device__ __forceinline__ int PHIDX(int x){   // x < 128
  return (x & ~31) | ((x & 1) << 4) | ((x & 31) >> 1);
}

// ------- merged prep: y<5 weight bf16-transpose (phi-permuted K), y==5 node qkv GEMV -------
__global__ void kprep(const float* wqkv_e, const float* e0_we, const float* e0_w1,
                      const float* e1_w1, const float* e1_w2,
                      const float* node, const float* wqkv_n,
                      unsigned short* WqkvT, unsigned short* WeT, unsigned short* W1T,
                      unsigned short* E1W1T, unsigned short* E1W2T,
                      float* qkvn){
  int m = blockIdx.y;
  int tid = threadIdx.x;
  if (m < 5){
    const float* src; unsigned short* dst; int K, Nn;
    if (m == 0){ src = wqkv_e; dst = WqkvT; K = 128; Nn = 512; }
    else if (m == 1){ src = e0_we; dst = WeT;   K = 256; Nn = 128; }
    else if (m == 2){ src = e0_w1; dst = W1T;   K = 128; Nn = 128; }
    else if (m == 3){ src = e1_w1; dst = E1W1T; K = 128; Nn = 256; }
    else            { src = e1_w2; dst = E1W2T; K = 256; Nn = 128; }
    int idx = blockIdx.x * 384 + tid;
    if (idx < K * Nn){
      int n = idx / K, k = idx % K;
      int ksrc = (m >= 2) ? ((k & ~127) | PHIDX(k & 127)) : k;  // bake channel-pair perm into K
      dst[idx] = f2bf(src[ksrc * Nn + n]);
    }
  } else {
    int row = blockIdx.x;
    __shared__ float sn[128];
    if (tid < 128) sn[tid] = node[row * 128 + tid];
    __syncthreads();
    float acc = 0.f;
    #pragma unroll 8
    for (int k = 0; k < 128; ++k) acc += sn[k] * wqkv_n[k * 384 + tid];
    qkvn[row * 384 + tid] = acc;
  }
}

// ---------------- fused: edge fp32 -> bf16 + meanJ (contiguous row pass) ----------------
__global__ void kprepA(const float* __restrict__ edge, unsigned short* __restrict__ E16,
                       float* __restrict__ meanJ){
  __shared__ float red[8][128];
  int bi = blockIdx.x; int tid = threadIdx.x;
  const float4* src = (const float4*)(edge + (size_t)bi * N_ * D_);
  uint2* gdst = (uint2*)E16 + (size_t)bi * (N_ * D_ / 4);
  float ps0 = 0.f, ps1 = 0.f, ps2 = 0.f, ps3 = 0.f;
  #pragma unroll 4
  for (int k = 0; k < 48; ++k){
    int idx = k * 256 + tid;
    float4 v = src[idx];
    uint2 o;
    o.x = f2bf_pk(v.x, v.y);
    o.y = f2bf_pk(v.z, v.w);
    gdst[idx] = o;
    ps0 += v.x; ps1 += v.y; ps2 += v.z; ps3 += v.w;
  }
  int g = tid >> 5, d0 = (tid & 31) * 4;
  red[g][d0] = ps0; red[g][d0 + 1] = ps1; red[g][d0 + 2] = ps2; red[g][d0 + 3] = ps3;
  __syncthreads();
  if (tid < 128){
    float s = 0.f;
    #pragma unroll
    for (int gg = 0; gg < 8; ++gg) s += red[gg][tid];
    meanJ[bi * 128 + tid] = s * (1.0f / N_);
  }
}

// ---- merged: y==0 attention (2 heads/wave, prefetch), y==1 meanI column pass ----
__global__ __launch_bounds__(256, 2) void kattnI(
    const unsigned short* __restrict__ E16, const unsigned short* __restrict__ WqkvT,
    const float* __restrict__ qkvn, float* __restrict__ attn,
    float* __restrict__ meanI){
  __shared__ float red[16][128];
  int tid = threadIdx.x;
  if (blockIdx.y == 1){
    int bj = blockIdx.x; int b = bj / N_, j = bj % N_;
    int ig = tid >> 4, dsub = tid & 15;
    float acc[8];
    #pragma unroll
    for (int e = 0; e < 8; ++e) acc[e] = 0.f;
    #pragma unroll 4
    for (int i = ig; i < N_; i += 16){
      const unsigned short* p = E16 + ((size_t)(b * N_ + i) * N_ + j) * D_ + dsub * 8;
      uint4 u = *(const uint4*)p;
      acc[0] += bf2f((unsigned short)(u.x & 0xffff)); acc[1] += bf2f((unsigned short)(u.x >> 16));
      acc[2] += bf2f((unsigned short)(u.y & 0xffff)); acc[3] += bf2f((unsigned short)(u.y >> 16));
      acc[4] += bf2f((unsigned short)(u.z & 0xffff)); acc[5] += bf2f((unsigned short)(u.z >> 16));
      acc[6] += bf2f((unsigned short)(u.w & 0xffff)); acc[7] += bf2f((unsigned short)(u.w >> 16));
    }
    #pragma unroll
    for (int e = 0; e < 8; ++e) red[ig][dsub * 8 + e] = acc[e];
    __syncthreads();
    if (tid < 128){
      float s = 0.f;
      #pragma unroll
      for (int gg = 0; gg < 16; ++gg) s += red[gg][tid];
      meanI[bj * 128 + tid] = s * (1.0f / N_);
    }
    return;
  }
  int bi = blockIdx.x; int b = bi / N_;
  int w = tid >> 6, lane = tid & 63, quad = lane >> 4, c16 = lane & 15;
  const float scale = 0.08838834764831845f;   // 1/sqrt(128)
  const unsigned short* Abase = E16 + (size_t)bi * N_ * D_;

  bh8 bf[2][4][4];
  #pragma unroll
  for (int s = 0; s < 2; ++s){
    int h = w + s * 4;
    #pragma unroll
    for (int u = 0; u < 4; ++u)
      #pragma unroll
      for (int ks = 0; ks < 4; ++ks){
        int col = h * 64 + u * 16 + c16;
        bf[s][u][ks] = *(const bh8*)(WqkvT + col * 128 + ks * 32 + quad * 8);
      }
  }
  float qv[2];
  #pragma unroll
  for (int s = 0; s < 2; ++s) qv[s] = qkvn[bi * 384 + (w + s * 4) * 48 + c16];

  float m_run[2] = {-1e30f, -1e30f}, l_run[2] = {0.f, 0.f}, o[2] = {0.f, 0.f};
  bh8 af[4];
  #pragma unroll
  for (int ks = 0; ks < 4; ++ks)
    af[ks] = *(const bh8*)(Abase + (size_t)c16 * D_ + ks * 32 + quad * 8);

  for (int jt = 0; jt < 24; ++jt){
    int jn = (jt + 1 < 24) ? jt + 1 : 0;
    bh8 afn[4];
    #pragma unroll
    for (int ks = 0; ks < 4; ++ks)
      afn[ks] = *(const bh8*)(Abase + (size_t)(jn * 16 + c16) * D_ + ks * 32 + quad * 8);
    float knv[2][4], vnv[2][4];
    const float* kvb = qkvn + ((size_t)b * N_ + jt * 16 + quad * 4) * 384;
    #pragma unroll
    for (int s = 0; s < 2; ++s)
      #pragma unroll
      for (int r = 0; r < 4; ++r){
        knv[s][r] = kvb[r * 384 + (w + s * 4) * 48 + 16 + c16];
        vnv[s][r] = kvb[r * 384 + (w + s * 4) * 48 + 32 + c16];
      }
    f32x4 EQ[2], EK[2], EV[2], EM[2];
    #pragma unroll
    for (int s = 0; s < 2; ++s){ EQ[s] = zero4(); EK[s] = zero4(); EV[s] = zero4(); EM[s] = zero4(); }
    #pragma unroll
    for (int ks = 0; ks < 4; ++ks)
      #pragma unroll
      for (int s = 0; s < 2; ++s){
        EQ[s] = mfma_bf16(af[ks], bf[s][0][ks], EQ[s]);
        EK[s] = mfma_bf16(af[ks], bf[s][1][ks], EK[s]);
        EV[s] = mfma_bf16(af[ks], bf[s][2][ks], EV[s]);
        EM[s] = mfma_bf16(af[ks], bf[s][3][ks], EM[s]);
      }
    #pragma unroll
    for (int s = 0; s < 2; ++s){
      float dots[4], vv[4];
      #pragma unroll
      for (int r = 0; r < 4; ++r){
        float t1 = (qv[s] + EQ[s][r]) * (knv[s][r] + EK[s][r]);
        dots[r] = red16_add(t1) * scale;
        vv[r] = vnv[s][r] * EM[s][r] + EV[s][r];
      }
      float tmax = fmaxf(fmaxf(dots[0], dots[1]), fmaxf(dots[2], dots[3]));
      tmax = fmaxf(tmax, __shfl_xor(tmax, 16));
      tmax = fmaxf(tmax, __shfl_xor(tmax, 32));
      float mnew = fmaxf(m_run[s], tmax);
      float al = __expf(m_run[s] - mnew);
      float p0 = __expf(dots[0] - mnew), p1 = __expf(dots[1] - mnew);
      float p2 = __expf(dots[2] - mnew), p3 = __expf(dots[3] - mnew);
      float lt = p0 + p1 + p2 + p3;
      lt += __shfl_xor(lt, 16); lt += __shfl_xor(lt, 32);
      l_run[s] = l_run[s] * al + lt;
      m_run[s] = mnew;
      o[s] = o[s] * al + p0 * vv[0] + p1 * vv[1] + p2 * vv[2] + p3 * vv[3];
    }
    #pragma unroll
    for (int ks = 0; ks < 4; ++ks) af[ks] = afn[ks];
  }
  #pragma unroll
  for (int s = 0; s < 2; ++s){
    float oo = o[s];
    oo += __shfl_xor(oo, 16); oo += __shfl_xor(oo, 32);
    oo /= l_run[s];
    if (quad == 0) attn[(size_t)bi * D_ + (w + s * 4) * 16 + c16] = oo;
  }
}

// -------- merged node path: lin0+LN0+MLP+LN1 then rowAdd/colAdd GEMVs --------
__global__ void knodeadd(const float* __restrict__ node, const float* __restrict__ attn,
                         const float* lin0_w, const float* lin0_b,
                         const float* g0, const float* bb0,
                         const float* w1, const float* w2, const float* b2,
                         const float* g1, const float* bb1,
                         const float* __restrict__ meanJ, const float* __restrict__ meanI,
                         const float* ws, const float* bs, const float* wt, const float* bt,
                         const float* wer, const float* wec, const float* be,
                         float* __restrict__ xOut,
                         float* __restrict__ rowAdd, float* __restrict__ colAdd){
  int row = blockIdx.x; int tid = threadIdx.x;
  __shared__ float sa[128], sx[128], sh[256], rb[8], sx2[128], smJ[128], smI[128];
  if (tid < 128){
    sa[tid] = attn[row * 128 + tid];
    smJ[tid] = meanJ[row * 128 + tid];
    smI[tid] = meanI[row * 128 + tid];
  }
  __syncthreads();
  float y = 0.f, x0 = 0.f;
  if (tid < 128){
    float acc = lin0_b[tid];
    #pragma unroll 8
    for (int k = 0; k < 128; ++k) acc += sa[k] * lin0_w[k * 128 + tid];
    y = acc + node[row * 128 + tid];
  }
  { float sv = (tid < 128) ? y : 0.f, sq = (tid < 128) ? y * y : 0.f;
    sv = red16_add(sv); sq = red16_add(sq);
    sv += __shfl_xor(sv, 16); sq += __shfl_xor(sq, 16);
    sv += __shfl_xor(sv, 32); sq += __shfl_xor(sq, 32);
    if ((tid & 63) == 0){ rb[tid >> 6] = sv; rb[4 + (tid >> 6)] = sq; } }
  __syncthreads();
  float mean = (rb[0] + rb[1] + rb[2] + rb[3]) * (1.f / 128.f);
  float var  = (rb[4] + rb[5] + rb[6] + rb[7]) * (1.f / 128.f) - mean * mean;
  float rstd = rsqrtf(var + 1e-5f);
  if (tid < 128){ x0 = (y - mean) * rstd * g0[tid] + bb0[tid]; sx[tid] = x0; }
  __syncthreads();
  { float acc = 0.f;
    #pragma unroll 8
    for (int k = 0; k < 128; ++k) acc += sx[k] * w1[k * 256 + tid];
    sh[tid] = geluf(acc); }
  __syncthreads();
  float y2 = 0.f;
  if (tid < 128){
    float acc = b2[tid];
    #pragma unroll 8
    for (int e = 0; e < 256; ++e) acc += sh[e] * w2[e * 128 + tid];
    y2 = acc + x0;
  }
  __syncthreads();
  { float sv = (tid < 128) ? y2 : 0.f, sq = (tid < 128) ? y2 * y2 : 0.f;
    sv = red16_add(sv); sq = red16_add(sq);
    sv += __shfl_xor(sv, 16); sq += __shfl_xor(sq, 16);
    sv += __shfl_xor(sv, 32); sq += __shfl_xor(sq, 32);
    if ((tid & 63) == 0){ rb[tid >> 6] = sv; rb[4 + (tid >> 6)] = sq; } }
  __syncthreads();
  mean = (rb[0] + rb[1] + rb[2] + rb[3]) * (1.f / 128.f);
  var  = (rb[4] + rb[5] + rb[6] + rb[7]) * (1.f / 128.f) - mean * mean;
  rstd = rsqrtf(var + 1e-5f);
  if (tid < 128){
    float xv = (y2 - mean) * rstd * g1[tid] + bb1[tid];
    xOut[row * 128 + tid] = xv;
    sx2[tid] = xv;
  }
  __syncthreads();
  if (tid < 128){
    int d = tid;
    float s1 = bs[d], s3 = 0.f;
    #pragma unroll 8
    for (int k = 0; k < 128; ++k){
      s1 += sx2[k] * ws[k * 128 + d];
      s3 += smJ[k] * wer[k * 128 + d];
    }
    rowAdd[row * 128 + d] = s1 + s3 + be[d];
  } else {
    int d = tid - 128;
    float s2 = bt[d], s4 = 0.f;
    #pragma unroll 8
    for (int k = 0; k < 128; ++k){
      s2 += sx2[k] * wt[k * 128 + d];
      s4 += smI[k] * wec[k * 128 + d];
    }
    colAdd[row * 128 + d] = s2 + s4;
  }
}

// -- fused edge pipeline v8: v7 structure (single 32 KiB LDS buffer, paired-channel
//    u32 LDS writes, float2 full-line stores) but launch_bounds (256,4):
//    128-VGPR budget fits the ~112-reg live set WITHOUT SPILL -> 4 blocks/CU.
//    (v7's (256,5) forced a 96-reg budget -> spill -> 640 MB scratch traffic.)
__global__ __launch_bounds__(256, 4) void kedge4(
    const unsigned short* __restrict__ E16, const unsigned short* __restrict__ WeT,
    const unsigned short* __restrict__ W1T, const unsigned short* __restrict__ E1W1T,
    const unsigned short* __restrict__ E1W2T,
    const float* __restrict__ rowAdd, const float* __restrict__ colAdd,
    const float* __restrict__ b1, const float* __restrict__ eg0, const float* __restrict__ eb0,
    const float* __restrict__ e1b2, const float* __restrict__ eg1, const float* __restrict__ eb1,
    float* __restrict__ eOut){
  __shared__ unsigned short sA[64][256];   // lo (p<128): K0-127 / edge2; hi (p>=128): K128-255 / stage buf
#define HIFV(i) (((float*)&sA[0][0])[ (((i) >> 6) << 7) + 64 + ((i) & 63) ])  // hi-half float alias
  int tid = threadIdx.x;
  int w = tid >> 6, lane = tid & 63, quad = lane >> 4, c16 = lane & 15;
  int R0 = blockIdx.x * 64;
  int b = R0 / NN; int rem = R0 % NN; int i = rem / N_; int j0 = rem % N_;

  // ---- prefetch G1 weights ----
  bh8 wb1[2][8];
  #pragma unroll
  for (int t = 0; t < 2; ++t)
    #pragma unroll
    for (int ks = 0; ks < 8; ++ks){
      int col = w * 32 + t * 16 + c16;
      wb1[t][ks] = *(const bh8*)(WeT + (size_t)col * 256 + ks * 32 + quad * 8);
    }

  // ---- stage A = [edge(b,i,j0+m,:) | edge(b,j0+m,i,:)] bf16, 64x256, chunk-XOR ----
  #pragma unroll
  for (int it = 0; it < 8; ++it){
    int cid = it * 256 + tid;
    int rrow = cid >> 5;
    int chunk = cid & 31;
    int kc = chunk * 8;
    const unsigned short* sp;
    if (kc < 128) sp = E16 + ((size_t)(b * N_ + i) * N_ + (j0 + rrow)) * D_ + kc;
    else          sp = E16 + ((size_t)(b * N_ + j0 + rrow) * N_ + i) * D_ + (kc - 128);
    *(float4*)&sA[rrow][(chunk ^ (rrow & 7)) << 3] = *(const float4*)sp;
  }
  __syncthreads();                                         // B1: staged

  // ---- G1 k-loop: A(64x256) @ WeT^T -> cols [32w,32w+32) ----
  f32x4 acc1[2][4];
  #pragma unroll
  for (int t = 0; t < 2; ++t) for (int ms = 0; ms < 4; ++ms) acc1[t][ms] = zero4();
  #pragma unroll
  for (int ks = 0; ks < 8; ++ks){
    bh8 af[4];
    #pragma unroll
    for (int ms = 0; ms < 4; ++ms){
      int row = ms * 16 + c16;
      af[ms] = *(const bh8*)&sA[row][swz(row, ks * 32 + quad * 8)];
    }
    #pragma unroll
    for (int t = 0; t < 2; ++t)
      #pragma unroll
      for (int ms = 0; ms < 4; ++ms)
        acc1[t][ms] = mfma_bf16(af[ms], wb1[t][ks], acc1[t][ms]);
  }
  // addends (short live range; latency hidden by B1.5 wait)
  float rAv[2], ca[2][16];
  #pragma unroll
  for (int t = 0; t < 2; ++t){
    rAv[t] = rowAdd[(b * N_ + i) * D_ + w * 32 + t * 16 + c16];
    #pragma unroll
    for (int ms = 0; ms < 4; ++ms)
      #pragma unroll
      for (int r = 0; r < 4; ++r)
        ca[t][ms * 4 + r] = colAdd[(size_t)(b * N_ + j0 + ms * 16 + quad * 4 + r) * D_
                                   + w * 32 + t * 16 + c16];
  }
  __syncthreads();                                         // B1.5: all hi-K reads done

  // ---- gelu1 -> hi (paired u32 at position sigma) ----
  #pragma unroll
  for (int ms = 0; ms < 4; ++ms)
    #pragma unroll
    for (int r = 0; r < 4; ++r){
      int m = ms * 16 + quad * 4 + r;
      float v0 = gelu_fast(acc1[0][ms][r] + rAv[0] + ca[0][ms * 4 + r]);
      float v1 = gelu_fast(acc1[1][ms][r] + rAv[1] + ca[1][ms * 4 + r]);
      *(unsigned*)&sA[m][swz(m, 128 + w * 32 + c16 * 2)] = f2bf_pk(v0, v1);
    }
  __syncthreads();                                         // B2: gelu1 ready

  // ---- G2: gelu1 @ W1T^T (phi-K) + b1 + raw edge residual ----
  bh8 wb2[2][4];
  #pragma unroll
  for (int t = 0; t < 2; ++t)
    #pragma unroll
    for (int ks = 0; ks < 4; ++ks){
      int col = w * 32 + t * 16 + c16;
      wb2[t][ks] = *(const bh8*)(W1T + (size_t)col * 128 + ks * 32 + quad * 8);
    }
  f32x4 acc2[2][4];
  #pragma unroll
  for (int t = 0; t < 2; ++t) for (int ms = 0; ms < 4; ++ms) acc2[t][ms] = zero4();
  #pragma unroll
  for (int ks = 0; ks < 4; ++ks){
    bh8 af[4];
    #pragma unroll
    for (int ms = 0; ms < 4; ++ms){
      int row = ms * 16 + c16;
      af[ms] = *(const bh8*)&sA[row][swz(row, 128 + ks * 32 + quad * 8)];
    }
    #pragma unroll
    for (int t = 0; t < 2; ++t)
      #pragma unroll
      for (int ms = 0; ms < 4; ++ms)
        acc2[t][ms] = mfma_bf16(af[ms], wb2[t][ks], acc2[t][ms]);
  }
  float b1v[2], g0v[2], b0v[2];
  #pragma unroll
  for (int t = 0; t < 2; ++t){
    int c = w * 32 + t * 16 + c16;
    b1v[t] = b1[c]; g0v[t] = eg0[c]; b0v[t] = eb0[c];
  }
  __syncthreads();                                         // B3a: gelu1 reads done (lr aliases hi)
  // ---- residual + LN0 partials (DPP) -> lr ----
  #pragma unroll
  for (int ms = 0; ms < 4; ++ms)
    #pragma unroll
    for (int r = 0; r < 4; ++r){
      int m = ms * 16 + quad * 4 + r;
      float s = 0.f, q = 0.f;
      #pragma unroll
      for (int t = 0; t < 2; ++t){
        float v = acc2[t][ms][r] + b1v[t] + bf2f(sA[m][swz(m, w * 32 + t * 16 + c16)]);
        acc2[t][ms][r] = v; s += v; q += v * v;
      }
      s = red16_add(s); q = red16_add(q);
      if (c16 == 0){ HIFV(w * 64 + m) = s; HIFV(256 + w * 64 + m) = q; }
    }
  __syncthreads();                                         // B3b: lr ready
  {                                                        // wave w -> stats rows [16w,16w+16)
    int src = lane & 3, mrow = w * 16 + (lane >> 2);
    float sp = HIFV(src * 64 + mrow), qp = HIFV(256 + src * 64 + mrow);
    sp = red4_add(sp); qp = red4_add(qp);
    if (src == 0){
      float mean = sp * (1.f / 128.f);
      float var  = qp * (1.f / 128.f) - mean * mean;
      HIFV(512 + 2 * mrow) = mean;
      HIFV(513 + 2 * mrow) = rsqrtf(var + 1e-5f);
    }
  }
  __syncthreads();                                         // B4a: stats ready
  // ---- LN0 finalize -> edge2 bf16 into lo (paired u32 at position sigma) ----
  #pragma unroll
  for (int ms = 0; ms < 4; ++ms)
    #pragma unroll
    for (int r = 0; r < 4; ++r){
      int m = ms * 16 + quad * 4 + r;
      float2 st = *(float2*)&HIFV(512 + 2 * m);
      float e0 = (acc2[0][ms][r] - st.x) * st.y * g0v[0] + b0v[0];
      float e1 = (acc2[1][ms][r] - st.x) * st.y * g0v[1] + b0v[1];
      *(unsigned*)&sA[m][swz(m, w * 32 + c16 * 2)] = f2bf_pk(e0, e1);
    }
  __syncthreads();                                         // B4b: edge2 ready

  // ---- G3/G4 two-phase over K=256 (hi = gelu3 stage buffer) ----
  f32x4 acc4[2][4];
  #pragma unroll
  for (int t = 0; t < 2; ++t) for (int ms = 0; ms < 4; ++ms) acc4[t][ms] = zero4();
  #pragma unroll
  for (int p = 0; p < 2; ++p){
    bh8 wb3[2][4];
    #pragma unroll
    for (int t = 0; t < 2; ++t)
      #pragma unroll
      for (int ks = 0; ks < 4; ++ks){
        int col = p * 128 + w * 32 + t * 16 + c16;
        wb3[t][ks] = *(const bh8*)(E1W1T + (size_t)col * 128 + ks * 32 + quad * 8);
      }
    f32x4 acc3[2][4];
    #pragma unroll
    for (int t = 0; t < 2; ++t) for (int ms = 0; ms < 4; ++ms) acc3[t][ms] = zero4();
    #pragma unroll
    for (int ks = 0; ks < 4; ++ks){
      bh8 af[4];
      #pragma unroll
      for (int ms = 0; ms < 4; ++ms){
        int row = ms * 16 + c16;
        af[ms] = *(const bh8*)&sA[row][swz(row, ks * 32 + quad * 8)];
      }
      #pragma unroll
      for (int t = 0; t < 2; ++t)
        #pragma unroll
        for (int ms = 0; ms < 4; ++ms)
          acc3[t][ms] = mfma_bf16(af[ms], wb3[t][ks], acc3[t][ms]);
    }
    #pragma unroll
    for (int ms = 0; ms < 4; ++ms)
      #pragma unroll
      for (int r = 0; r < 4; ++r){
        int m = ms * 16 + quad * 4 + r;
        float v0 = gelu_fast(acc3[0][ms][r]);
        float v1 = gelu_fast(acc3[1][ms][r]);
        *(unsigned*)&sA[m][swz(m, 128 + w * 32 + c16 * 2)] = f2bf_pk(v0, v1);
      }
    __syncthreads();                                       // B5: gelu3 phase p ready
    bh8 wb4[2][4];
    #pragma unroll
    for (int t = 0; t < 2; ++t)
      #pragma unroll
      for (int k2 = 0; k2 < 4; ++k2){
        int pcol = w * 32 + c16 * 2 + t;                   // paired output column
        wb4[t][k2] = *(const bh8*)(E1W2T + (size_t)pcol * 256 + p * 128 + k2 * 32 + quad * 8);
      }
    #pragma unroll
    for (int k2 = 0; k2 < 4; ++k2){
      bh8 af[4];
      #pragma unroll
      for (int ms = 0; ms < 4; ++ms){
        int row = ms * 16 + c16;
        af[ms] = *(const bh8*)&sA[row][swz(row, 128 + k2 * 32 + quad * 8)];
      }
      #pragma unroll
      for (int t = 0; t < 2; ++t)
        #pragma unroll
        for (int ms = 0; ms < 4; ++ms)
          acc4[t][ms] = mfma_bf16(af[ms], wb4[t][k2], acc4[t][ms]);
    }
    __syncthreads();                                       // B6: hi reads done
  }

  // ---- G4 epilogue: + b2 + edge2 residual -> LN1 (DPP) -> full-line store ----
  float b2v[2], g1v[2], bb1v[2]; int slv[2];
  #pragma unroll
  for (int t = 0; t < 2; ++t){
    int pcol = w * 32 + c16 * 2 + t;
    b2v[t] = e1b2[pcol]; g1v[t] = eg1[pcol]; bb1v[t] = eb1[pcol];
    int lo5 = c16 * 2 + t;
    slv[t] = w * 32 + (((lo5 & 15) << 1) | (lo5 >> 4));    // sigma(pcol): edge2 storage position
  }
  #pragma unroll
  for (int ms = 0; ms < 4; ++ms)
    #pragma unroll
    for (int r = 0; r < 4; ++r){
      int m = ms * 16 + quad * 4 + r;
      float s = 0.f, q = 0.f;
      #pragma unroll
      for (int t = 0; t < 2; ++t){
        float v = acc4[t][ms][r] + b2v[t] + bf2f(sA[m][swz(m, slv[t])]);
        acc4[t][ms][r] = v; s += v; q += v * v;
      }
      s = red16_add(s); q = red16_add(q);
      if (c16 == 0){ HIFV(w * 64 + m) = s; HIFV(256 + w * 64 + m) = q; }
    }
  __syncthreads();                                         // B9: lr ready
  {
    int src = lane & 3, mrow = w * 16 + (lane >> 2);
    float sp = HIFV(src * 64 + mrow), qp = HIFV(256 + src * 64 + mrow);
    sp = red4_add(sp); qp = red4_add(qp);
    if (src == 0){
      float mean = sp * (1.f / 128.f);
      float var  = qp * (1.f / 128.f) - mean * mean;
      HIFV(512 + 2 * mrow) = mean;
      HIFV(513 + 2 * mrow) = rsqrtf(var + 1e-5f);
    }
  }
  __syncthreads();                                         // B10: stats ready
  float* outBase = eOut + ((size_t)(b * N_ + i) * N_ + j0) * D_;
  #pragma unroll
  for (int ms = 0; ms < 4; ++ms)
    #pragma unroll
    for (int r = 0; r < 4; ++r){
      int m = ms * 16 + quad * 4 + r;
      float2 st = *(float2*)&HIFV(512 + 2 * m);
      float2 ov;
      ov.x = (acc4[0][ms][r] - st.x) * st.y * g1v[0] + bb1v[0];
      ov.y = (acc4[1][ms][r] - st.x) * st.y * g1v[1] + bb1v[1];
      *(float2*)&outBase[(size_t)m * D_ + w * 32 + c16 * 2] = ov;   // 128B line per row per instr
    }
#undef HIFV
}

extern "C" void kernel_launch(void* const* d_in, const int* in_sizes, int n_in,
                              void* d_out, int out_size, void* d_ws, size_t ws_size,
                              hipStream_t stream){
  const float* node   = (const float*)d_in[0];
  const float* edge   = (const float*)d_in[1];
  const float* wqkv_n = (const float*)d_in[3];
  const float* wqkv_e = (const float*)d_in[4];
  const float* lin0_w = (const float*)d_in[5];
  const float* lin0_b = (const float*)d_in[6];
  const float* ln0_g  = (const float*)d_in[7];
  const float* ln0_b  = (const float*)d_in[8];
  const float* ln1_g  = (const float*)d_in[9];
  const float* ln1_b  = (const float*)d_in[10];
  const float* nmlp_w1= (const float*)d_in[11];
  const float* nmlp_w2= (const float*)d_in[12];
  const float* nmlp_b2= (const float*)d_in[13];
  const float* e0_we  = (const float*)d_in[14];
  const float* e0_be  = (const float*)d_in[15];
  const float* e0_ws  = (const float*)d_in[16];
  const float* e0_bs  = (const float*)d_in[17];
  const float* e0_wt  = (const float*)d_in[18];
  const float* e0_bt  = (const float*)d_in[19];
  const float* e0_wer = (const float*)d_in[20];
  const float* e0_wec = (const float*)d_in[21];
  const float* e0_w1  = (const float*)d_in[22];
  const float* e0_b1  = (const float*)d_in[23];
  const float* e1_w1  = (const float*)d_in[24];
  const float* e1_w2  = (const float*)d_in[25];
  const float* e1_b2  = (const float*)d_in[26];
  const float* eln0_g = (const float*)d_in[27];
  const float* eln0_b = (const float*)d_in[28];
  const float* eln1_g = (const float*)d_in[29];
  const float* eln1_b = (const float*)d_in[30];

  unsigned short* E16   = (unsigned short*)d_ws;
  unsigned short* WqkvT = E16 + (size_t)EDGE_ELEMS;
  unsigned short* WeT   = WqkvT + 65536;
  unsigned short* W1T   = WeT + 32768;
  unsigned short* E1W1T = W1T + 16384;
  unsigned short* E1W2T = E1W1T + 32768;
  float* fbase  = (float*)(E1W2T + 32768);
  float* qkvn   = fbase;
  float* attn   = qkvn + (size_t)BN * 384;
  float* meanJ  = attn + NODE_ELEMS;
  float* meanI  = meanJ + NODE_ELEMS;
  float* rowAdd = meanI + NODE_ELEMS;
  float* colAdd = rowAdd + NODE_ELEMS;

  float* xOut = (float*)d_out;
  float* eOut = xOut + NODE_ELEMS;

  kprep<<<dim3(BN, 6), 384, 0, stream>>>(wqkv_e, e0_we, e0_w1, e1_w1, e1_w2,
                                         node, wqkv_n,
                                         WqkvT, WeT, W1T, E1W1T, E1W2T, qkvn);
  kprepA<<<BN, 256, 0, stream>>>(edge, E16, meanJ);
  kattnI<<<dim3(BN, 2), 256, 0, stream>>>(E16, WqkvT, qkvn, attn, meanI);
  knodeadd<<<BN, 256, 0, stream>>>(node, attn, lin0_w, lin0_b, ln0_g, ln0_b,
                                   nmlp_w1, nmlp_w2, nmlp_b2, ln1_g, ln1_b,
                                   meanJ, meanI, e0_ws, e0_bs, e0_wt, e0_bt,
                                   e0_wer, e0_wec, e0_be,
                                   xOut, rowAdd, colAdd);
  kedge4<<<NN * B_ / 64, 256, 0, stream>>>(E16, WeT, W1T, E1W1T, E1W2T,
                                           rowAdd, colAdd, e0_b1,
                                           eln0_g, eln0_b, e1_b2, eln1_g, eln1_b,
                                           eOut);
}

// Round 5
// 638.739 us; speedup vs baseline: 1.2559x; 1.0287x over previous
//
#include <hip/hip_runtime.h>
#include <hip/hip_bf16.h>
#include <cstdint>
#include <cstddef>

#define B_ 2
#define N_ 384
#define D_ 128
#define NN (N_*N_)                  // 147456
#define BN (B_*N_)                  // 768
#define EDGE_ELEMS (B_*NN*D_)       // 37748736
#define NODE_ELEMS (BN*D_)          // 98304

typedef short bh8 __attribute__((ext_vector_type(8)));
typedef float f32x4 __attribute__((ext_vector_type(4)));

__device__ __forceinline__ f32x4 mfma_bf16(bh8 a, bh8 b, f32x4 c){
  return __builtin_amdgcn_mfma_f32_16x16x32_bf16(a, b, c, 0, 0, 0);
}
__device__ __forceinline__ unsigned short f2bf(float f){
  unsigned u = __float_as_uint(f);
  return (unsigned short)((u + 0x7fffu + ((u >> 16) & 1u)) >> 16);
}
__device__ __forceinline__ unsigned f2bf_pk(float a, float b){   // packed cvt: lo=a, hi=b
  __hip_bfloat162 h = __float22bfloat162_rn(make_float2(a, b));
  return *(unsigned*)&h;
}
__device__ __forceinline__ float bf2f(unsigned short h){
  return __uint_as_float(((unsigned)h) << 16);
}
__device__ __forceinline__ float geluf(float x){        // exact (node path)
  return 0.5f * x * (1.0f + erff(x * 0.70710678118654752f));
}
__device__ __forceinline__ float gelu_fast(float x){    // tanh approx via hw exp
  float x2 = x * x;
  float t  = __fmaf_rn(0.044715f * x, x2, x);
  float e  = __expf(1.5957691216057308f * t);
  float r  = __builtin_amdgcn_rcpf(e + 1.0f);
  return x - x * r;
}
__device__ __forceinline__ f32x4 zero4(){ f32x4 z = {0.f,0.f,0.f,0.f}; return z; }

// ---- DPP reductions (VALU pipe) ----
__device__ __forceinline__ float red16_add(float x){
  x += __int_as_float(__builtin_amdgcn_update_dpp(0, __float_as_int(x), 0xB1, 0xF, 0xF, true));  // quad_perm [1,0,3,2]
  x += __int_as_float(__builtin_amdgcn_update_dpp(0, __float_as_int(x), 0x4E, 0xF, 0xF, true));  // quad_perm [2,3,0,1]
  x += __int_as_float(__builtin_amdgcn_update_dpp(0, __float_as_int(x), 0x141, 0xF, 0xF, true)); // row_half_mirror
  x += __int_as_float(__builtin_amdgcn_update_dpp(0, __float_as_int(x), 0x140, 0xF, 0xF, true)); // row_mirror
  return x;
}
__device__ __forceinline__ float red4_add(float x){
  x += __int_as_float(__builtin_amdgcn_update_dpp(0, __float_as_int(x), 0xB1, 0xF, 0xF, true));
  x += __int_as_float(__builtin_amdgcn_update_dpp(0, __float_as_int(x), 0x4E, 0xF, 0xF, true));
  return x;
}
// XOR chunk swizzle: logical (row m, short-pos p in 0..255) -> physical short index.
// Only the low 3 bits of the 16B-chunk index are XORed -> valid for lo (K/edge2) and hi (stage) halves.
__device__ __forceinline__ int swz(int m, int p){
  return ((((p >> 3) ^ (m & 7)) << 3) | (p & 7));
}
// channel-pairing permutation: position p holds channel phi(p) (rotate-right of low 5 bits);
// storage position of channel c is sigma(c) = rotate-left of low 5 bits.
__device__ __forceinline__ int PHIDX(int x){   // x < 128
  return (x & ~31) | ((x & 1) << 4) | ((x & 31) >> 1);
}

// ------- merged prep: y<5 weight bf16-transpose (phi-permuted K), y==5 node qkv GEMV -------
__global__ void kprep(const float* wqkv_e, const float* e0_we, const float* e0_w1,
                      const float* e1_w1, const float* e1_w2,
                      const float* node, const float* wqkv_n,
                      unsigned short* WqkvT, unsigned short* WeT, unsigned short* W1T,
                      unsigned short* E1W1T, unsigned short* E1W2T,
                      float* qkvn){
  int m = blockIdx.y;
  int tid = threadIdx.x;
  if (m < 5){
    const float* src; unsigned short* dst; int K, Nn;
    if (m == 0){ src = wqkv_e; dst = WqkvT; K = 128; Nn = 512; }
    else if (m == 1){ src = e0_we; dst = WeT;   K = 256; Nn = 128; }
    else if (m == 2){ src = e0_w1; dst = W1T;   K = 128; Nn = 128; }
    else if (m == 3){ src = e1_w1; dst = E1W1T; K = 128; Nn = 256; }
    else            { src = e1_w2; dst = E1W2T; K = 256; Nn = 128; }
    int idx = blockIdx.x * 384 + tid;
    if (idx < K * Nn){
      int n = idx / K, k = idx % K;
      int ksrc = (m >= 2) ? ((k & ~127) | PHIDX(k & 127)) : k;  // bake channel-pair perm into K
      dst[idx] = f2bf(src[ksrc * Nn + n]);
    }
  } else {
    int row = blockIdx.x;
    __shared__ float sn[128];
    if (tid < 128) sn[tid] = node[row * 128 + tid];
    __syncthreads();
    float acc = 0.f;
    #pragma unroll 8
    for (int k = 0; k < 128; ++k) acc += sn[k] * wqkv_n[k * 384 + tid];
    qkvn[row * 384 + tid] = acc;
  }
}

// ---------------- fused: edge fp32 -> bf16 + meanJ (contiguous row pass) ----------------
__global__ void kprepA(const float* __restrict__ edge, unsigned short* __restrict__ E16,
                       float* __restrict__ meanJ){
  __shared__ float red[8][128];
  int bi = blockIdx.x; int tid = threadIdx.x;
  const float4* src = (const float4*)(edge + (size_t)bi * N_ * D_);
  uint2* gdst = (uint2*)E16 + (size_t)bi * (N_ * D_ / 4);
  float ps0 = 0.f, ps1 = 0.f, ps2 = 0.f, ps3 = 0.f;
  #pragma unroll 4
  for (int k = 0; k < 48; ++k){
    int idx = k * 256 + tid;
    float4 v = src[idx];
    uint2 o;
    o.x = f2bf_pk(v.x, v.y);
    o.y = f2bf_pk(v.z, v.w);
    gdst[idx] = o;
    ps0 += v.x; ps1 += v.y; ps2 += v.z; ps3 += v.w;
  }
  int g = tid >> 5, d0 = (tid & 31) * 4;
  red[g][d0] = ps0; red[g][d0 + 1] = ps1; red[g][d0 + 2] = ps2; red[g][d0 + 3] = ps3;
  __syncthreads();
  if (tid < 128){
    float s = 0.f;
    #pragma unroll
    for (int gg = 0; gg < 8; ++gg) s += red[gg][tid];
    meanJ[bi * 128 + tid] = s * (1.0f / N_);
  }
}

// ---- merged: y==0 attention (2 heads/wave, prefetch), y==1 meanI column pass ----
__global__ __launch_bounds__(256, 2) void kattnI(
    const unsigned short* __restrict__ E16, const unsigned short* __restrict__ WqkvT,
    const float* __restrict__ qkvn, float* __restrict__ attn,
    float* __restrict__ meanI){
  __shared__ float red[16][128];
  int tid = threadIdx.x;
  if (blockIdx.y == 1){
    int bj = blockIdx.x; int b = bj / N_, j = bj % N_;
    int ig = tid >> 4, dsub = tid & 15;
    float acc[8];
    #pragma unroll
    for (int e = 0; e < 8; ++e) acc[e] = 0.f;
    #pragma unroll 4
    for (int i = ig; i < N_; i += 16){
      const unsigned short* p = E16 + ((size_t)(b * N_ + i) * N_ + j) * D_ + dsub * 8;
      uint4 u = *(const uint4*)p;
      acc[0] += bf2f((unsigned short)(u.x & 0xffff)); acc[1] += bf2f((unsigned short)(u.x >> 16));
      acc[2] += bf2f((unsigned short)(u.y & 0xffff)); acc[3] += bf2f((unsigned short)(u.y >> 16));
      acc[4] += bf2f((unsigned short)(u.z & 0xffff)); acc[5] += bf2f((unsigned short)(u.z >> 16));
      acc[6] += bf2f((unsigned short)(u.w & 0xffff)); acc[7] += bf2f((unsigned short)(u.w >> 16));
    }
    #pragma unroll
    for (int e = 0; e < 8; ++e) red[ig][dsub * 8 + e] = acc[e];
    __syncthreads();
    if (tid < 128){
      float s = 0.f;
      #pragma unroll
      for (int gg = 0; gg < 16; ++gg) s += red[gg][tid];
      meanI[bj * 128 + tid] = s * (1.0f / N_);
    }
    return;
  }
  int bi = blockIdx.x; int b = bi / N_;
  int w = tid >> 6, lane = tid & 63, quad = lane >> 4, c16 = lane & 15;
  const float scale = 0.08838834764831845f;   // 1/sqrt(128)
  const unsigned short* Abase = E16 + (size_t)bi * N_ * D_;

  bh8 bf[2][4][4];
  #pragma unroll
  for (int s = 0; s < 2; ++s){
    int h = w + s * 4;
    #pragma unroll
    for (int u = 0; u < 4; ++u)
      #pragma unroll
      for (int ks = 0; ks < 4; ++ks){
        int col = h * 64 + u * 16 + c16;
        bf[s][u][ks] = *(const bh8*)(WqkvT + col * 128 + ks * 32 + quad * 8);
      }
  }
  float qv[2];
  #pragma unroll
  for (int s = 0; s < 2; ++s) qv[s] = qkvn[bi * 384 + (w + s * 4) * 48 + c16];

  float m_run[2] = {-1e30f, -1e30f}, l_run[2] = {0.f, 0.f}, o[2] = {0.f, 0.f};
  bh8 af[4];
  #pragma unroll
  for (int ks = 0; ks < 4; ++ks)
    af[ks] = *(const bh8*)(Abase + (size_t)c16 * D_ + ks * 32 + quad * 8);

  for (int jt = 0; jt < 24; ++jt){
    int jn = (jt + 1 < 24) ? jt + 1 : 0;
    bh8 afn[4];
    #pragma unroll
    for (int ks = 0; ks < 4; ++ks)
      afn[ks] = *(const bh8*)(Abase + (size_t)(jn * 16 + c16) * D_ + ks * 32 + quad * 8);
    float knv[2][4], vnv[2][4];
    const float* kvb = qkvn + ((size_t)b * N_ + jt * 16 + quad * 4) * 384;
    #pragma unroll
    for (int s = 0; s < 2; ++s)
      #pragma unroll
      for (int r = 0; r < 4; ++r){
        knv[s][r] = kvb[r * 384 + (w + s * 4) * 48 + 16 + c16];
        vnv[s][r] = kvb[r * 384 + (w + s * 4) * 48 + 32 + c16];
      }
    f32x4 EQ[2], EK[2], EV[2], EM[2];
    #pragma unroll
    for (int s = 0; s < 2; ++s){ EQ[s] = zero4(); EK[s] = zero4(); EV[s] = zero4(); EM[s] = zero4(); }
    #pragma unroll
    for (int ks = 0; ks < 4; ++ks)
      #pragma unroll
      for (int s = 0; s < 2; ++s){
        EQ[s] = mfma_bf16(af[ks], bf[s][0][ks], EQ[s]);
        EK[s] = mfma_bf16(af[ks], bf[s][1][ks], EK[s]);
        EV[s] = mfma_bf16(af[ks], bf[s][2][ks], EV[s]);
        EM[s] = mfma_bf16(af[ks], bf[s][3][ks], EM[s]);
      }
    #pragma unroll
    for (int s = 0; s < 2; ++s){
      float dots[4], vv[4];
      #pragma unroll
      for (int r = 0; r < 4; ++r){
        float t1 = (qv[s] + EQ[s][r]) * (knv[s][r] + EK[s][r]);
        dots[r] = red16_add(t1) * scale;
        vv[r] = vnv[s][r] * EM[s][r] + EV[s][r];
      }
      float tmax = fmaxf(fmaxf(dots[0], dots[1]), fmaxf(dots[2], dots[3]));
      tmax = fmaxf(tmax, __shfl_xor(tmax, 16));
      tmax = fmaxf(tmax, __shfl_xor(tmax, 32));
      float mnew = fmaxf(m_run[s], tmax);
      float al = __expf(m_run[s] - mnew);
      float p0 = __expf(dots[0] - mnew), p1 = __expf(dots[1] - mnew);
      float p2 = __expf(dots[2] - mnew), p3 = __expf(dots[3] - mnew);
      float lt = p0 + p1 + p2 + p3;
      lt += __shfl_xor(lt, 16); lt += __shfl_xor(lt, 32);
      l_run[s] = l_run[s] * al + lt;
      m_run[s] = mnew;
      o[s] = o[s] * al + p0 * vv[0] + p1 * vv[1] + p2 * vv[2] + p3 * vv[3];
    }
    #pragma unroll
    for (int ks = 0; ks < 4; ++ks) af[ks] = afn[ks];
  }
  #pragma unroll
  for (int s = 0; s < 2; ++s){
    float oo = o[s];
    oo += __shfl_xor(oo, 16); oo += __shfl_xor(oo, 32);
    oo /= l_run[s];
    if (quad == 0) attn[(size_t)bi * D_ + (w + s * 4) * 16 + c16] = oo;
  }
}

// -------- merged node path: lin0+LN0+MLP+LN1 then rowAdd/colAdd GEMVs --------
__global__ void knodeadd(const float* __restrict__ node, const float* __restrict__ attn,
                         const float* lin0_w, const float* lin0_b,
                         const float* g0, const float* bb0,
                         const float* w1, const float* w2, const float* b2,
                         const float* g1, const float* bb1,
                         const float* __restrict__ meanJ, const float* __restrict__ meanI,
                         const float* ws, const float* bs, const float* wt, const float* bt,
                         const float* wer, const float* wec, const float* be,
                         float* __restrict__ xOut,
                         float* __restrict__ rowAdd, float* __restrict__ colAdd){
  int row = blockIdx.x; int tid = threadIdx.x;
  __shared__ float sa[128], sx[128], sh[256], rb[8], sx2[128], smJ[128], smI[128];
  if (tid < 128){
    sa[tid] = attn[row * 128 + tid];
    smJ[tid] = meanJ[row * 128 + tid];
    smI[tid] = meanI[row * 128 + tid];
  }
  __syncthreads();
  float y = 0.f, x0 = 0.f;
  if (tid < 128){
    float acc = lin0_b[tid];
    #pragma unroll 8
    for (int k = 0; k < 128; ++k) acc += sa[k] * lin0_w[k * 128 + tid];
    y = acc + node[row * 128 + tid];
  }
  { float sv = (tid < 128) ? y : 0.f, sq = (tid < 128) ? y * y : 0.f;
    sv = red16_add(sv); sq = red16_add(sq);
    sv += __shfl_xor(sv, 16); sq += __shfl_xor(sq, 16);
    sv += __shfl_xor(sv, 32); sq += __shfl_xor(sq, 32);
    if ((tid & 63) == 0){ rb[tid >> 6] = sv; rb[4 + (tid >> 6)] = sq; } }
  __syncthreads();
  float mean = (rb[0] + rb[1] + rb[2] + rb[3]) * (1.f / 128.f);
  float var  = (rb[4] + rb[5] + rb[6] + rb[7]) * (1.f / 128.f) - mean * mean;
  float rstd = rsqrtf(var + 1e-5f);
  if (tid < 128){ x0 = (y - mean) * rstd * g0[tid] + bb0[tid]; sx[tid] = x0; }
  __syncthreads();
  { float acc = 0.f;
    #pragma unroll 8
    for (int k = 0; k < 128; ++k) acc += sx[k] * w1[k * 256 + tid];
    sh[tid] = geluf(acc); }
  __syncthreads();
  float y2 = 0.f;
  if (tid < 128){
    float acc = b2[tid];
    #pragma unroll 8
    for (int e = 0; e < 256; ++e) acc += sh[e] * w2[e * 128 + tid];
    y2 = acc + x0;
  }
  __syncthreads();
  { float sv = (tid < 128) ? y2 : 0.f, sq = (tid < 128) ? y2 * y2 : 0.f;
    sv = red16_add(sv); sq = red16_add(sq);
    sv += __shfl_xor(sv, 16); sq += __shfl_xor(sq, 16);
    sv += __shfl_xor(sv, 32); sq += __shfl_xor(sq, 32);
    if ((tid & 63) == 0){ rb[tid >> 6] = sv; rb[4 + (tid >> 6)] = sq; } }
  __syncthreads();
  mean = (rb[0] + rb[1] + rb[2] + rb[3]) * (1.f / 128.f);
  var  = (rb[4] + rb[5] + rb[6] + rb[7]) * (1.f / 128.f) - mean * mean;
  rstd = rsqrtf(var + 1e-5f);
  if (tid < 128){
    float xv = (y2 - mean) * rstd * g1[tid] + bb1[tid];
    xOut[row * 128 + tid] = xv;
    sx2[tid] = xv;
  }
  __syncthreads();
  if (tid < 128){
    int d = tid;
    float s1 = bs[d], s3 = 0.f;
    #pragma unroll 8
    for (int k = 0; k < 128; ++k){
      s1 += sx2[k] * ws[k * 128 + d];
      s3 += smJ[k] * wer[k * 128 + d];
    }
    rowAdd[row * 128 + d] = s1 + s3 + be[d];
  } else {
    int d = tid - 128;
    float s2 = bt[d], s4 = 0.f;
    #pragma unroll 8
    for (int k = 0; k < 128; ++k){
      s2 += sx2[k] * wt[k * 128 + d];
      s4 += smI[k] * wec[k * 128 + d];
    }
    colAdd[row * 128 + d] = s2 + s4;
  }
}

// -- fused edge pipeline v9: v8 (32 KiB LDS, paired channels, full-line stores)
//    + register-pressure surgery so (256,4) truly fits WITHOUT spill:
//      * G1 weights loaded in two K-halves through ONE wb1[2][4] (32 regs, was 64),
//        kh loop kept rolled (#pragma unroll 1) so the allocator can't rename.
//      * rowAdd/colAdd loads moved AFTER the B1.5 barrier (scheduling fence) so
//        they can't be hoisted across the G1 MFMA loop (was +34 live regs).
//      * G3/G4 p-loop kept rolled so p=1 weight loads can't hoist into p=0.
__global__ __launch_bounds__(256, 4) void kedge4(
    const unsigned short* __restrict__ E16, const unsigned short* __restrict__ WeT,
    const unsigned short* __restrict__ W1T, const unsigned short* __restrict__ E1W1T,
    const unsigned short* __restrict__ E1W2T,
    const float* __restrict__ rowAdd, const float* __restrict__ colAdd,
    const float* __restrict__ b1, const float* __restrict__ eg0, const float* __restrict__ eb0,
    const float* __restrict__ e1b2, const float* __restrict__ eg1, const float* __restrict__ eb1,
    float* __restrict__ eOut){
  __shared__ unsigned short sA[64][256];   // lo (p<128): K0-127 / edge2; hi (p>=128): K128-255 / stage buf
#define HIFV(i) (((float*)&sA[0][0])[ (((i) >> 6) << 7) + 64 + ((i) & 63) ])  // hi-half float alias
  int tid = threadIdx.x;
  int w = tid >> 6, lane = tid & 63, quad = lane >> 4, c16 = lane & 15;
  int R0 = blockIdx.x * 64;
  int b = R0 / NN; int rem = R0 % NN; int i = rem / N_; int j0 = rem % N_;

  // ---- stage A = [edge(b,i,j0+m,:) | edge(b,j0+m,i,:)] bf16, 64x256, chunk-XOR ----
  #pragma unroll
  for (int it = 0; it < 8; ++it){
    int cid = it * 256 + tid;
    int rrow = cid >> 5;
    int chunk = cid & 31;
    int kc = chunk * 8;
    const unsigned short* sp;
    if (kc < 128) sp = E16 + ((size_t)(b * N_ + i) * N_ + (j0 + rrow)) * D_ + kc;
    else          sp = E16 + ((size_t)(b * N_ + j0 + rrow) * N_ + i) * D_ + (kc - 128);
    *(float4*)&sA[rrow][(chunk ^ (rrow & 7)) << 3] = *(const float4*)sp;
  }
  __syncthreads();                                         // B1: staged

  // ---- G1: A(64x256) @ WeT^T -> cols [32w,32w+32), two K-halves ----
  f32x4 acc1[2][4];
  #pragma unroll
  for (int t = 0; t < 2; ++t) for (int ms = 0; ms < 4; ++ms) acc1[t][ms] = zero4();
  {
    bh8 wb1[2][4];
    #pragma unroll 1
    for (int kh = 0; kh < 2; ++kh){          // rolled: caps wb1 at 32 VGPRs (WAR reuse)
      #pragma unroll
      for (int t = 0; t < 2; ++t)
        #pragma unroll
        for (int ks = 0; ks < 4; ++ks){
          int col = w * 32 + t * 16 + c16;
          wb1[t][ks] = *(const bh8*)(WeT + (size_t)col * 256 + (kh * 4 + ks) * 32 + quad * 8);
        }
      #pragma unroll
      for (int ks = 0; ks < 4; ++ks){
        bh8 af[4];
        #pragma unroll
        for (int ms = 0; ms < 4; ++ms){
          int row = ms * 16 + c16;
          af[ms] = *(const bh8*)&sA[row][swz(row, (kh * 4 + ks) * 32 + quad * 8)];
        }
        #pragma unroll
        for (int t = 0; t < 2; ++t)
          #pragma unroll
          for (int ms = 0; ms < 4; ++ms)
            acc1[t][ms] = mfma_bf16(af[ms], wb1[t][ks], acc1[t][ms]);
      }
    }
  }
  __syncthreads();                                         // B1.5: all hi-K reads done

  // ---- addends loaded HERE (post-barrier fence: cannot hoist into G1 loop) ----
  float rAv[2], ca[2][16];
  #pragma unroll
  for (int t = 0; t < 2; ++t){
    rAv[t] = rowAdd[(b * N_ + i) * D_ + w * 32 + t * 16 + c16];
    #pragma unroll
    for (int ms = 0; ms < 4; ++ms)
      #pragma unroll
      for (int r = 0; r < 4; ++r)
        ca[t][ms * 4 + r] = colAdd[(size_t)(b * N_ + j0 + ms * 16 + quad * 4 + r) * D_
                                   + w * 32 + t * 16 + c16];
  }
  // ---- gelu1 -> hi (paired u32 at position sigma) ----
  #pragma unroll
  for (int ms = 0; ms < 4; ++ms)
    #pragma unroll
    for (int r = 0; r < 4; ++r){
      int m = ms * 16 + quad * 4 + r;
      float v0 = gelu_fast(acc1[0][ms][r] + rAv[0] + ca[0][ms * 4 + r]);
      float v1 = gelu_fast(acc1[1][ms][r] + rAv[1] + ca[1][ms * 4 + r]);
      *(unsigned*)&sA[m][swz(m, 128 + w * 32 + c16 * 2)] = f2bf_pk(v0, v1);
    }
  __syncthreads();                                         // B2: gelu1 ready

  // ---- G2: gelu1 @ W1T^T (phi-K) + b1 + raw edge residual ----
  bh8 wb2[2][4];
  #pragma unroll
  for (int t = 0; t < 2; ++t)
    #pragma unroll
    for (int ks = 0; ks < 4; ++ks){
      int col = w * 32 + t * 16 + c16;
      wb2[t][ks] = *(const bh8*)(W1T + (size_t)col * 128 + ks * 32 + quad * 8);
    }
  f32x4 acc2[2][4];
  #pragma unroll
  for (int t = 0; t < 2; ++t) for (int ms = 0; ms < 4; ++ms) acc2[t][ms] = zero4();
  #pragma unroll
  for (int ks = 0; ks < 4; ++ks){
    bh8 af[4];
    #pragma unroll
    for (int ms = 0; ms < 4; ++ms){
      int row = ms * 16 + c16;
      af[ms] = *(const bh8*)&sA[row][swz(row, 128 + ks * 32 + quad * 8)];
    }
    #pragma unroll
    for (int t = 0; t < 2; ++t)
      #pragma unroll
      for (int ms = 0; ms < 4; ++ms)
        acc2[t][ms] = mfma_bf16(af[ms], wb2[t][ks], acc2[t][ms]);
  }
  float b1v[2], g0v[2], b0v[2];
  #pragma unroll
  for (int t = 0; t < 2; ++t){
    int c = w * 32 + t * 16 + c16;
    b1v[t] = b1[c]; g0v[t] = eg0[c]; b0v[t] = eb0[c];
  }
  __syncthreads();                                         // B3a: gelu1 reads done (lr aliases hi)
  // ---- residual + LN0 partials (DPP) -> lr ----
  #pragma unroll
  for (int ms = 0; ms < 4; ++ms)
    #pragma unroll
    for (int r = 0; r < 4; ++r){
      int m = ms * 16 + quad * 4 + r;
      float s = 0.f, q = 0.f;
      #pragma unroll
      for (int t = 0; t < 2; ++t){
        float v = acc2[t][ms][r] + b1v[t] + bf2f(sA[m][swz(m, w * 32 + t * 16 + c16)]);
        acc2[t][ms][r] = v; s += v; q += v * v;
      }
      s = red16_add(s); q = red16_add(q);
      if (c16 == 0){ HIFV(w * 64 + m) = s; HIFV(256 + w * 64 + m) = q; }
    }
  __syncthreads();                                         // B3b: lr ready
  {                                                        // wave w -> stats rows [16w,16w+16)
    int src = lane & 3, mrow = w * 16 + (lane >> 2);
    float sp = HIFV(src * 64 + mrow), qp = HIFV(256 + src * 64 + mrow);
    sp = red4_add(sp); qp = red4_add(qp);
    if (src == 0){
      float mean = sp * (1.f / 128.f);
      float var  = qp * (1.f / 128.f) - mean * mean;
      HIFV(512 + 2 * mrow) = mean;
      HIFV(513 + 2 * mrow) = rsqrtf(var + 1e-5f);
    }
  }
  __syncthreads();                                         // B4a: stats ready
  // ---- LN0 finalize -> edge2 bf16 into lo (paired u32 at position sigma) ----
  #pragma unroll
  for (int ms = 0; ms < 4; ++ms)
    #pragma unroll
    for (int r = 0; r < 4; ++r){
      int m = ms * 16 + quad * 4 + r;
      float2 st = *(float2*)&HIFV(512 + 2 * m);
      float e0 = (acc2[0][ms][r] - st.x) * st.y * g0v[0] + b0v[0];
      float e1 = (acc2[1][ms][r] - st.x) * st.y * g0v[1] + b0v[1];
      *(unsigned*)&sA[m][swz(m, w * 32 + c16 * 2)] = f2bf_pk(e0, e1);
    }
  __syncthreads();                                         // B4b: edge2 ready

  // ---- G3/G4 two-phase over K=256 (hi = gelu3 stage buffer) ----
  f32x4 acc4[2][4];
  #pragma unroll
  for (int t = 0; t < 2; ++t) for (int ms = 0; ms < 4; ++ms) acc4[t][ms] = zero4();
  #pragma unroll 1
  for (int p = 0; p < 2; ++p){             // rolled: p=1 weight loads can't hoist into p=0
    bh8 wb3[2][4];
    #pragma unroll
    for (int t = 0; t < 2; ++t)
      #pragma unroll
      for (int ks = 0; ks < 4; ++ks){
        int col = p * 128 + w * 32 + t * 16 + c16;
        wb3[t][ks] = *(const bh8*)(E1W1T + (size_t)col * 128 + ks * 32 + quad * 8);
      }
    f32x4 acc3[2][4];
    #pragma unroll
    for (int t = 0; t < 2; ++t) for (int ms = 0; ms < 4; ++ms) acc3[t][ms] = zero4();
    #pragma unroll
    for (int ks = 0; ks < 4; ++ks){
      bh8 af[4];
      #pragma unroll
      for (int ms = 0; ms < 4; ++ms){
        int row = ms * 16 + c16;
        af[ms] = *(const bh8*)&sA[row][swz(row, ks * 32 + quad * 8)];
      }
      #pragma unroll
      for (int t = 0; t < 2; ++t)
        #pragma unroll
        for (int ms = 0; ms < 4; ++ms)
          acc3[t][ms] = mfma_bf16(af[ms], wb3[t][ks], acc3[t][ms]);
    }
    #pragma unroll
    for (int ms = 0; ms < 4; ++ms)
      #pragma unroll
      for (int r = 0; r < 4; ++r){
        int m = ms * 16 + quad * 4 + r;
        float v0 = gelu_fast(acc3[0][ms][r]);
        float v1 = gelu_fast(acc3[1][ms][r]);
        *(unsigned*)&sA[m][swz(m, 128 + w * 32 + c16 * 2)] = f2bf_pk(v0, v1);
      }
    __syncthreads();                                       // B5: gelu3 phase p ready
    bh8 wb4[2][4];
    #pragma unroll
    for (int t = 0; t < 2; ++t)
      #pragma unroll
      for (int k2 = 0; k2 < 4; ++k2){
        int pcol = w * 32 + c16 * 2 + t;                   // paired output column
        wb4[t][k2] = *(const bh8*)(E1W2T + (size_t)pcol * 256 + p * 128 + k2 * 32 + quad * 8);
      }
    #pragma unroll
    for (int k2 = 0; k2 < 4; ++k2){
      bh8 af[4];
      #pragma unroll
      for (int ms = 0; ms < 4; ++ms){
        int row = ms * 16 + c16;
        af[ms] = *(const bh8*)&sA[row][swz(row, 128 + k2 * 32 + quad * 8)];
      }
      #pragma unroll
      for (int t = 0; t < 2; ++t)
        #pragma unroll
        for (int ms = 0; ms < 4; ++ms)
          acc4[t][ms] = mfma_bf16(af[ms], wb4[t][k2], acc4[t][ms]);
    }
    __syncthreads();                                       // B6: hi reads done
  }

  // ---- G4 epilogue: + b2 + edge2 residual -> LN1 (DPP) -> full-line store ----
  float b2v[2], g1v[2], bb1v[2]; int slv[2];
  #pragma unroll
  for (int t = 0; t < 2; ++t){
    int pcol = w * 32 + c16 * 2 + t;
    b2v[t] = e1b2[pcol]; g1v[t] = eg1[pcol]; bb1v[t] = eb1[pcol];
    int lo5 = c16 * 2 + t;
    slv[t] = w * 32 + (((lo5 & 15) << 1) | (lo5 >> 4));    // sigma(pcol): edge2 storage position
  }
  #pragma unroll
  for (int ms = 0; ms < 4; ++ms)
    #pragma unroll
    for (int r = 0; r < 4; ++r){
      int m = ms * 16 + quad * 4 + r;
      float s = 0.f, q = 0.f;
      #pragma unroll
      for (int t = 0; t < 2; ++t){
        float v = acc4[t][ms][r] + b2v[t] + bf2f(sA[m][swz(m, slv[t])]);
        acc4[t][ms][r] = v; s += v; q += v * v;
      }
      s = red16_add(s); q = red16_add(q);
      if (c16 == 0){ HIFV(w * 64 + m) = s; HIFV(256 + w * 64 + m) = q; }
    }
  __syncthreads();                                         // B9: lr ready
  {
    int src = lane & 3, mrow = w * 16 + (lane >> 2);
    float sp = HIFV(src * 64 + mrow), qp = HIFV(256 + src * 64 + mrow);
    sp = red4_add(sp); qp = red4_add(qp);
    if (src == 0){
      float mean = sp * (1.f / 128.f);
      float var  = qp * (1.f / 128.f) - mean * mean;
      HIFV(512 + 2 * mrow) = mean;
      HIFV(513 + 2 * mrow) = rsqrtf(var + 1e-5f);
    }
  }
  __syncthreads();                                         // B10: stats ready
  float* outBase = eOut + ((size_t)(b * N_ + i) * N_ + j0) * D_;
  #pragma unroll
  for (int ms = 0; ms < 4; ++ms)
    #pragma unroll
    for (int r = 0; r < 4; ++r){
      int m = ms * 16 + quad * 4 + r;
      float2 st = *(float2*)&HIFV(512 + 2 * m);
      float2 ov;
      ov.x = (acc4[0][ms][r] - st.x) * st.y * g1v[0] + bb1v[0];
      ov.y = (acc4[1][ms][r] - st.x) * st.y * g1v[1] + bb1v[1];
      *(float2*)&outBase[(size_t)m * D_ + w * 32 + c16 * 2] = ov;   // 128B line per row per instr
    }
#undef HIFV
}

extern "C" void kernel_launch(void* const* d_in, const int* in_sizes, int n_in,
                              void* d_out, int out_size, void* d_ws, size_t ws_size,
                              hipStream_t stream){
  const float* node   = (const float*)d_in[0];
  const float* edge   = (const float*)d_in[1];
  const float* wqkv_n = (const float*)d_in[3];
  const float* wqkv_e = (const float*)d_in[4];
  const float* lin0_w = (const float*)d_in[5];
  const float* lin0_b = (const float*)d_in[6];
  const float* ln0_g  = (const float*)d_in[7];
  const float* ln0_b  = (const float*)d_in[8];
  const float* ln1_g  = (const float*)d_in[9];
  const float* ln1_b  = (const float*)d_in[10];
  const float* nmlp_w1= (const float*)d_in[11];
  const float* nmlp_w2= (const float*)d_in[12];
  const float* nmlp_b2= (const float*)d_in[13];
  const float* e0_we  = (const float*)d_in[14];
  const float* e0_be  = (const float*)d_in[15];
  const float* e0_ws  = (const float*)d_in[16];
  const float* e0_bs  = (const float*)d_in[17];
  const float* e0_wt  = (const float*)d_in[18];
  const float* e0_bt  = (const float*)d_in[19];
  const float* e0_wer = (const float*)d_in[20];
  const float* e0_wec = (const float*)d_in[21];
  const float* e0_w1  = (const float*)d_in[22];
  const float* e0_b1  = (const float*)d_in[23];
  const float* e1_w1  = (const float*)d_in[24];
  const float* e1_w2  = (const float*)d_in[25];
  const float* e1_b2  = (const float*)d_in[26];
  const float* eln0_g = (const float*)d_in[27];
  const float* eln0_b = (const float*)d_in[28];
  const float* eln1_g = (const float*)d_in[29];
  const float* eln1_b = (const float*)d_in[30];

  unsigned short* E16   = (unsigned short*)d_ws;
  unsigned short* WqkvT = E16 + (size_t)EDGE_ELEMS;
  unsigned short* WeT   = WqkvT + 65536;
  unsigned short* W1T   = WeT + 32768;
  unsigned short* E1W1T = W1T + 16384;
  unsigned short* E1W2T = E1W1T + 32768;
  float* fbase  = (float*)(E1W2T + 32768);
  float* qkvn   = fbase;
  float* attn   = qkvn + (size_t)BN * 384;
  float* meanJ  = attn + NODE_ELEMS;
  float* meanI  = meanJ + NODE_ELEMS;
  float* rowAdd = meanI + NODE_ELEMS;
  float* colAdd = rowAdd + NODE_ELEMS;

  float* xOut = (float*)d_out;
  float* eOut = xOut + NODE_ELEMS;

  kprep<<<dim3(BN, 6), 384, 0, stream>>>(wqkv_e, e0_we, e0_w1, e1_w1, e1_w2,
                                         node, wqkv_n,
                                         WqkvT, WeT, W1T, E1W1T, E1W2T, qkvn);
  kprepA<<<BN, 256, 0, stream>>>(edge, E16, meanJ);
  kattnI<<<dim3(BN, 2), 256, 0, stream>>>(E16, WqkvT, qkvn, attn, meanI);
  knodeadd<<<BN, 256, 0, stream>>>(node, attn, lin0_w, lin0_b, ln0_g, ln0_b,
                                   nmlp_w1, nmlp_w2, nmlp_b2, ln1_g, ln1_b,
                                   meanJ, meanI, e0_ws, e0_bs, e0_wt, e0_bt,
                                   e0_wer, e0_wec, e0_be,
                                   xOut, rowAdd, colAdd);
  kedge4<<<NN * B_ / 64, 256, 0, stream>>>(E16, WeT, W1T, E1W1T, E1W2T,
                                           rowAdd, colAdd, e0_b1,
                                           eln0_g, eln0_b, e1_b2, eln1_g, eln1_b,
                                           eOut);
}

// Round 7
// 631.505 us; speedup vs baseline: 1.2702x; 1.0115x over previous
//
#include <hip/hip_runtime.h>
#include <hip/hip_bf16.h>
#include <cstdint>
#include <cstddef>

#define B_ 2
#define N_ 384
#define D_ 128
#define NN (N_*N_)                  // 147456
#define BN (B_*N_)                  // 768
#define EDGE_ELEMS (B_*NN*D_)       // 37748736
#define NODE_ELEMS (BN*D_)          // 98304

typedef short bh8 __attribute__((ext_vector_type(8)));
typedef float f32x4 __attribute__((ext_vector_type(4)));

__device__ __forceinline__ f32x4 mfma_bf16(bh8 a, bh8 b, f32x4 c){
  return __builtin_amdgcn_mfma_f32_16x16x32_bf16(a, b, c, 0, 0, 0);
}
__device__ __forceinline__ unsigned short f2bf(float f){
  unsigned u = __float_as_uint(f);
  return (unsigned short)((u + 0x7fffu + ((u >> 16) & 1u)) >> 16);
}
__device__ __forceinline__ unsigned f2bf_pk(float a, float b){   // packed cvt: lo=a, hi=b
  __hip_bfloat162 h = __float22bfloat162_rn(make_float2(a, b));
  return *(unsigned*)&h;
}
__device__ __forceinline__ float bf2f(unsigned short h){
  return __uint_as_float(((unsigned)h) << 16);
}
__device__ __forceinline__ float geluf(float x){        // exact (node path)
  return 0.5f * x * (1.0f + erff(x * 0.70710678118654752f));
}
__device__ __forceinline__ float gelu_fast(float x){    // tanh approx via hw exp
  float x2 = x * x;
  float t  = __fmaf_rn(0.044715f * x, x2, x);
  float e  = __expf(1.5957691216057308f * t);
  float r  = __builtin_amdgcn_rcpf(e + 1.0f);
  return x - x * r;
}
__device__ __forceinline__ f32x4 zero4(){ f32x4 z = {0.f,0.f,0.f,0.f}; return z; }

// ---- DPP reductions (VALU pipe) ----
__device__ __forceinline__ float red16_add(float x){
  x += __int_as_float(__builtin_amdgcn_update_dpp(0, __float_as_int(x), 0xB1, 0xF, 0xF, true));  // quad_perm [1,0,3,2]
  x += __int_as_float(__builtin_amdgcn_update_dpp(0, __float_as_int(x), 0x4E, 0xF, 0xF, true));  // quad_perm [2,3,0,1]
  x += __int_as_float(__builtin_amdgcn_update_dpp(0, __float_as_int(x), 0x141, 0xF, 0xF, true)); // row_half_mirror
  x += __int_as_float(__builtin_amdgcn_update_dpp(0, __float_as_int(x), 0x140, 0xF, 0xF, true)); // row_mirror
  return x;
}
__device__ __forceinline__ float red4_add(float x){
  x += __int_as_float(__builtin_amdgcn_update_dpp(0, __float_as_int(x), 0xB1, 0xF, 0xF, true));
  x += __int_as_float(__builtin_amdgcn_update_dpp(0, __float_as_int(x), 0x4E, 0xF, 0xF, true));
  return x;
}
// XOR chunk swizzle: logical (row m, short-pos p in 0..255) -> physical short index.
__device__ __forceinline__ int swz(int m, int p){
  return ((((p >> 3) ^ (m & 7)) << 3) | (p & 7));
}
// channel-pairing permutation: position p holds channel phi(p) (rotate-right of low 5 bits);
// storage position of channel c is sigma(c) = rotate-left of low 5 bits.
__device__ __forceinline__ int PHIDX(int x){   // x < 128
  return (x & ~31) | ((x & 1) << 4) | ((x & 31) >> 1);
}

// ------- merged prep: y<5 weight bf16-transpose (phi-permuted K), y==5 node qkv GEMV -------
__global__ void kprep(const float* wqkv_e, const float* e0_we, const float* e0_w1,
                      const float* e1_w1, const float* e1_w2,
                      const float* node, const float* wqkv_n,
                      unsigned short* WqkvT, unsigned short* WeT, unsigned short* W1T,
                      unsigned short* E1W1T, unsigned short* E1W2T,
                      float* qkvn){
  int m = blockIdx.y;
  int tid = threadIdx.x;
  if (m < 5){
    const float* src; unsigned short* dst; int K, Nn;
    if (m == 0){ src = wqkv_e; dst = WqkvT; K = 128; Nn = 512; }
    else if (m == 1){ src = e0_we; dst = WeT;   K = 256; Nn = 128; }
    else if (m == 2){ src = e0_w1; dst = W1T;   K = 128; Nn = 128; }
    else if (m == 3){ src = e1_w1; dst = E1W1T; K = 128; Nn = 256; }
    else            { src = e1_w2; dst = E1W2T; K = 256; Nn = 128; }
    int idx = blockIdx.x * 384 + tid;
    if (idx < K * Nn){
      int n = idx / K, k = idx % K;
      int ksrc = (m >= 2) ? ((k & ~127) | PHIDX(k & 127)) : k;  // bake channel-pair perm into K
      dst[idx] = f2bf(src[ksrc * Nn + n]);
    }
  } else {
    int row = blockIdx.x;
    __shared__ float sn[128];
    if (tid < 128) sn[tid] = node[row * 128 + tid];
    __syncthreads();
    float acc = 0.f;
    #pragma unroll 8
    for (int k = 0; k < 128; ++k) acc += sn[k] * wqkv_n[k * 384 + tid];
    qkvn[row * 384 + tid] = acc;
  }
}

// ---------------- fused: edge fp32 -> bf16 + meanJ (contiguous row pass) ----------------
__global__ void kprepA(const float* __restrict__ edge, unsigned short* __restrict__ E16,
                       float* __restrict__ meanJ){
  __shared__ float red[8][128];
  int bi = blockIdx.x; int tid = threadIdx.x;
  const float4* src = (const float4*)(edge + (size_t)bi * N_ * D_);
  uint2* gdst = (uint2*)E16 + (size_t)bi * (N_ * D_ / 4);
  float ps0 = 0.f, ps1 = 0.f, ps2 = 0.f, ps3 = 0.f;
  #pragma unroll 4
  for (int k = 0; k < 48; ++k){
    int idx = k * 256 + tid;
    float4 v = src[idx];
    uint2 o;
    o.x = f2bf_pk(v.x, v.y);
    o.y = f2bf_pk(v.z, v.w);
    gdst[idx] = o;
    ps0 += v.x; ps1 += v.y; ps2 += v.z; ps3 += v.w;
  }
  int g = tid >> 5, d0 = (tid & 31) * 4;
  red[g][d0] = ps0; red[g][d0 + 1] = ps1; red[g][d0 + 2] = ps2; red[g][d0 + 3] = ps3;
  __syncthreads();
  if (tid < 128){
    float s = 0.f;
    #pragma unroll
    for (int gg = 0; gg < 8; ++gg) s += red[gg][tid];
    meanJ[bi * 128 + tid] = s * (1.0f / N_);
  }
}

// ---- merged: y==0 attention (2 heads/wave, prefetch), y==1 meanI column pass ----
__global__ __launch_bounds__(256, 2) void kattnI(
    const unsigned short* __restrict__ E16, const unsigned short* __restrict__ WqkvT,
    const float* __restrict__ qkvn, float* __restrict__ attn,
    float* __restrict__ meanI){
  __shared__ float red[16][128];
  int tid = threadIdx.x;
  if (blockIdx.y == 1){
    int bj = blockIdx.x; int b = bj / N_, j = bj % N_;
    int ig = tid >> 4, dsub = tid & 15;
    float acc[8];
    #pragma unroll
    for (int e = 0; e < 8; ++e) acc[e] = 0.f;
    #pragma unroll 4
    for (int i = ig; i < N_; i += 16){
      const unsigned short* p = E16 + ((size_t)(b * N_ + i) * N_ + j) * D_ + dsub * 8;
      uint4 u = *(const uint4*)p;
      acc[0] += bf2f((unsigned short)(u.x & 0xffff)); acc[1] += bf2f((unsigned short)(u.x >> 16));
      acc[2] += bf2f((unsigned short)(u.y & 0xffff)); acc[3] += bf2f((unsigned short)(u.y >> 16));
      acc[4] += bf2f((unsigned short)(u.z & 0xffff)); acc[5] += bf2f((unsigned short)(u.z >> 16));
      acc[6] += bf2f((unsigned short)(u.w & 0xffff)); acc[7] += bf2f((unsigned short)(u.w >> 16));
    }
    #pragma unroll
    for (int e = 0; e < 8; ++e) red[ig][dsub * 8 + e] = acc[e];
    __syncthreads();
    if (tid < 128){
      float s = 0.f;
      #pragma unroll
      for (int gg = 0; gg < 16; ++gg) s += red[gg][tid];
      meanI[bj * 128 + tid] = s * (1.0f / N_);
    }
    return;
  }
  int bi = blockIdx.x; int b = bi / N_;
  int w = tid >> 6, lane = tid & 63, quad = lane >> 4, c16 = lane & 15;
  const float scale = 0.08838834764831845f;   // 1/sqrt(128)
  const unsigned short* Abase = E16 + (size_t)bi * N_ * D_;

  bh8 bf[2][4][4];
  #pragma unroll
  for (int s = 0; s < 2; ++s){
    int h = w + s * 4;
    #pragma unroll
    for (int u = 0; u < 4; ++u)
      #pragma unroll
      for (int ks = 0; ks < 4; ++ks){
        int col = h * 64 + u * 16 + c16;
        bf[s][u][ks] = *(const bh8*)(WqkvT + col * 128 + ks * 32 + quad * 8);
      }
  }
  float qv[2];
  #pragma unroll
  for (int s = 0; s < 2; ++s) qv[s] = qkvn[bi * 384 + (w + s * 4) * 48 + c16];

  float m_run[2] = {-1e30f, -1e30f}, l_run[2] = {0.f, 0.f}, o[2] = {0.f, 0.f};
  bh8 af[4];
  #pragma unroll
  for (int ks = 0; ks < 4; ++ks)
    af[ks] = *(const bh8*)(Abase + (size_t)c16 * D_ + ks * 32 + quad * 8);

  for (int jt = 0; jt < 24; ++jt){
    int jn = (jt + 1 < 24) ? jt + 1 : 0;
    bh8 afn[4];
    #pragma unroll
    for (int ks = 0; ks < 4; ++ks)
      afn[ks] = *(const bh8*)(Abase + (size_t)(jn * 16 + c16) * D_ + ks * 32 + quad * 8);
    float knv[2][4], vnv[2][4];
    const float* kvb = qkvn + ((size_t)b * N_ + jt * 16 + quad * 4) * 384;
    #pragma unroll
    for (int s = 0; s < 2; ++s)
      #pragma unroll
      for (int r = 0; r < 4; ++r){
        knv[s][r] = kvb[r * 384 + (w + s * 4) * 48 + 16 + c16];
        vnv[s][r] = kvb[r * 384 + (w + s * 4) * 48 + 32 + c16];
      }
    f32x4 EQ[2], EK[2], EV[2], EM[2];
    #pragma unroll
    for (int s = 0; s < 2; ++s){ EQ[s] = zero4(); EK[s] = zero4(); EV[s] = zero4(); EM[s] = zero4(); }
    #pragma unroll
    for (int ks = 0; ks < 4; ++ks)
      #pragma unroll
      for (int s = 0; s < 2; ++s){
        EQ[s] = mfma_bf16(af[ks], bf[s][0][ks], EQ[s]);
        EK[s] = mfma_bf16(af[ks], bf[s][1][ks], EK[s]);
        EV[s] = mfma_bf16(af[ks], bf[s][2][ks], EV[s]);
        EM[s] = mfma_bf16(af[ks], bf[s][3][ks], EM[s]);
      }
    #pragma unroll
    for (int s = 0; s < 2; ++s){
      float dots[4], vv[4];
      #pragma unroll
      for (int r = 0; r < 4; ++r){
        float t1 = (qv[s] + EQ[s][r]) * (knv[s][r] + EK[s][r]);
        dots[r] = red16_add(t1) * scale;
        vv[r] = vnv[s][r] * EM[s][r] + EV[s][r];
      }
      float tmax = fmaxf(fmaxf(dots[0], dots[1]), fmaxf(dots[2], dots[3]));
      tmax = fmaxf(tmax, __shfl_xor(tmax, 16));
      tmax = fmaxf(tmax, __shfl_xor(tmax, 32));
      float mnew = fmaxf(m_run[s], tmax);
      float al = __expf(m_run[s] - mnew);
      float p0 = __expf(dots[0] - mnew), p1 = __expf(dots[1] - mnew);
      float p2 = __expf(dots[2] - mnew), p3 = __expf(dots[3] - mnew);
      float lt = p0 + p1 + p2 + p3;
      lt += __shfl_xor(lt, 16); lt += __shfl_xor(lt, 32);
      l_run[s] = l_run[s] * al + lt;
      m_run[s] = mnew;
      o[s] = o[s] * al + p0 * vv[0] + p1 * vv[1] + p2 * vv[2] + p3 * vv[3];
    }
    #pragma unroll
    for (int ks = 0; ks < 4; ++ks) af[ks] = afn[ks];
  }
  #pragma unroll
  for (int s = 0; s < 2; ++s){
    float oo = o[s];
    oo += __shfl_xor(oo, 16); oo += __shfl_xor(oo, 32);
    oo /= l_run[s];
    if (quad == 0) attn[(size_t)bi * D_ + (w + s * 4) * 16 + c16] = oo;
  }
}

// -------- merged node path: lin0+LN0+MLP+LN1 then rowAdd/colAdd GEMVs --------
__global__ void knodeadd(const float* __restrict__ node, const float* __restrict__ attn,
                         const float* lin0_w, const float* lin0_b,
                         const float* g0, const float* bb0,
                         const float* w1, const float* w2, const float* b2,
                         const float* g1, const float* bb1,
                         const float* __restrict__ meanJ, const float* __restrict__ meanI,
                         const float* ws, const float* bs, const float* wt, const float* bt,
                         const float* wer, const float* wec, const float* be,
                         float* __restrict__ xOut,
                         float* __restrict__ rowAdd, float* __restrict__ colAdd){
  int row = blockIdx.x; int tid = threadIdx.x;
  __shared__ float sa[128], sx[128], sh[256], rb[8], sx2[128], smJ[128], smI[128];
  if (tid < 128){
    sa[tid] = attn[row * 128 + tid];
    smJ[tid] = meanJ[row * 128 + tid];
    smI[tid] = meanI[row * 128 + tid];
  }
  __syncthreads();
  float y = 0.f, x0 = 0.f;
  if (tid < 128){
    float acc = lin0_b[tid];
    #pragma unroll 8
    for (int k = 0; k < 128; ++k) acc += sa[k] * lin0_w[k * 128 + tid];
    y = acc + node[row * 128 + tid];
  }
  { float sv = (tid < 128) ? y : 0.f, sq = (tid < 128) ? y * y : 0.f;
    sv = red16_add(sv); sq = red16_add(sq);
    sv += __shfl_xor(sv, 16); sq += __shfl_xor(sq, 16);
    sv += __shfl_xor(sv, 32); sq += __shfl_xor(sq, 32);
    if ((tid & 63) == 0){ rb[tid >> 6] = sv; rb[4 + (tid >> 6)] = sq; } }
  __syncthreads();
  float mean = (rb[0] + rb[1] + rb[2] + rb[3]) * (1.f / 128.f);
  float var  = (rb[4] + rb[5] + rb[6] + rb[7]) * (1.f / 128.f) - mean * mean;
  float rstd = rsqrtf(var + 1e-5f);
  if (tid < 128){ x0 = (y - mean) * rstd * g0[tid] + bb0[tid]; sx[tid] = x0; }
  __syncthreads();
  { float acc = 0.f;
    #pragma unroll 8
    for (int k = 0; k < 128; ++k) acc += sx[k] * w1[k * 256 + tid];
    sh[tid] = geluf(acc); }
  __syncthreads();
  float y2 = 0.f;
  if (tid < 128){
    float acc = b2[tid];
    #pragma unroll 8
    for (int e = 0; e < 256; ++e) acc += sh[e] * w2[e * 128 + tid];
    y2 = acc + x0;
  }
  __syncthreads();
  { float sv = (tid < 128) ? y2 : 0.f, sq = (tid < 128) ? y2 * y2 : 0.f;
    sv = red16_add(sv); sq = red16_add(sq);
    sv += __shfl_xor(sv, 16); sq += __shfl_xor(sq, 16);
    sv += __shfl_xor(sv, 32); sq += __shfl_xor(sq, 32);
    if ((tid & 63) == 0){ rb[tid >> 6] = sv; rb[4 + (tid >> 6)] = sq; } }
  __syncthreads();
  mean = (rb[0] + rb[1] + rb[2] + rb[3]) * (1.f / 128.f);
  var  = (rb[4] + rb[5] + rb[6] + rb[7]) * (1.f / 128.f) - mean * mean;
  rstd = rsqrtf(var + 1e-5f);
  if (tid < 128){
    float xv = (y2 - mean) * rstd * g1[tid] + bb1[tid];
    xOut[row * 128 + tid] = xv;
    sx2[tid] = xv;
  }
  __syncthreads();
  if (tid < 128){
    int d = tid;
    float s1 = bs[d], s3 = 0.f;
    #pragma unroll 8
    for (int k = 0; k < 128; ++k){
      s1 += sx2[k] * ws[k * 128 + d];
      s3 += smJ[k] * wer[k * 128 + d];
    }
    rowAdd[row * 128 + d] = s1 + s3 + be[d];
  } else {
    int d = tid - 128;
    float s2 = bt[d], s4 = 0.f;
    #pragma unroll 8
    for (int k = 0; k < 128; ++k){
      s2 += sx2[k] * wt[k * 128 + d];
      s4 += smI[k] * wec[k * 128 + d];
    }
    colAdd[row * 128 + d] = s2 + s4;
  }
}

// -- fused edge pipeline v10: v8 body (32 KiB aliased LDS, paired-channel u32 LDS
//    writes, full-line float2 stores, full unrolls) at launch_bounds (256,3):
//    170-reg budget fits the ~150-reg live set with ZERO spill (v6 proved the
//    operating point; v8/v9 proved 128-reg budgets always spill ~300-600 MB).
//    Launched as TWO half-grid dispatches (base arg) so the rocprof top-5 table
//    also exposes the other kernels' timings (diagnostic for next round).
__global__ __launch_bounds__(256, 3) void kedge4(
    const unsigned short* __restrict__ E16, const unsigned short* __restrict__ WeT,
    const unsigned short* __restrict__ W1T, const unsigned short* __restrict__ E1W1T,
    const unsigned short* __restrict__ E1W2T,
    const float* __restrict__ rowAdd, const float* __restrict__ colAdd,
    const float* __restrict__ b1, const float* __restrict__ eg0, const float* __restrict__ eb0,
    const float* __restrict__ e1b2, const float* __restrict__ eg1, const float* __restrict__ eb1,
    float* __restrict__ eOut, int base){
  __shared__ unsigned short sA[64][256];   // lo (p<128): K0-127 / edge2; hi (p>=128): K128-255 / stage buf
#define HIFV(i) (((float*)&sA[0][0])[ (((i) >> 6) << 7) + 64 + ((i) & 63) ])  // hi-half float alias
  int tid = threadIdx.x;
  int w = tid >> 6, lane = tid & 63, quad = lane >> 4, c16 = lane & 15;
  int R0 = (base + blockIdx.x) * 64;
  int b = R0 / NN; int rem = R0 % NN; int i = rem / N_; int j0 = rem % N_;

  // ---- prefetch G1 weights ----
  bh8 wb1[2][8];
  #pragma unroll
  for (int t = 0; t < 2; ++t)
    #pragma unroll
    for (int ks = 0; ks < 8; ++ks){
      int col = w * 32 + t * 16 + c16;
      wb1[t][ks] = *(const bh8*)(WeT + (size_t)col * 256 + ks * 32 + quad * 8);
    }

  // ---- stage A = [edge(b,i,j0+m,:) | edge(b,j0+m,i,:)] bf16, 64x256, chunk-XOR ----
  #pragma unroll
  for (int it = 0; it < 8; ++it){
    int cid = it * 256 + tid;
    int rrow = cid >> 5;
    int chunk = cid & 31;
    int kc = chunk * 8;
    const unsigned short* sp;
    if (kc < 128) sp = E16 + ((size_t)(b * N_ + i) * N_ + (j0 + rrow)) * D_ + kc;
    else          sp = E16 + ((size_t)(b * N_ + j0 + rrow) * N_ + i) * D_ + (kc - 128);
    *(float4*)&sA[rrow][(chunk ^ (rrow & 7)) << 3] = *(const float4*)sp;
  }
  __syncthreads();                                         // B1: staged

  // ---- G1 k-loop: A(64x256) @ WeT^T -> cols [32w,32w+32) ----
  f32x4 acc1[2][4];
  #pragma unroll
  for (int t = 0; t < 2; ++t) for (int ms = 0; ms < 4; ++ms) acc1[t][ms] = zero4();
  #pragma unroll
  for (int ks = 0; ks < 8; ++ks){
    bh8 af[4];
    #pragma unroll
    for (int ms = 0; ms < 4; ++ms){
      int row = ms * 16 + c16;
      af[ms] = *(const bh8*)&sA[row][swz(row, ks * 32 + quad * 8)];
    }
    #pragma unroll
    for (int t = 0; t < 2; ++t)
      #pragma unroll
      for (int ms = 0; ms < 4; ++ms)
        acc1[t][ms] = mfma_bf16(af[ms], wb1[t][ks], acc1[t][ms]);
  }
  // addends (short live range; latency hidden by B1.5 wait)
  float rAv[2], ca[2][16];
  #pragma unroll
  for (int t = 0; t < 2; ++t){
    rAv[t] = rowAdd[(b * N_ + i) * D_ + w * 32 + t * 16 + c16];
    #pragma unroll
    for (int ms = 0; ms < 4; ++ms)
      #pragma unroll
      for (int r = 0; r < 4; ++r)
        ca[t][ms * 4 + r] = colAdd[(size_t)(b * N_ + j0 + ms * 16 + quad * 4 + r) * D_
                                   + w * 32 + t * 16 + c16];
  }
  __syncthreads();                                         // B1.5: all hi-K reads done

  // ---- gelu1 -> hi (paired u32 at position sigma) ----
  #pragma unroll
  for (int ms = 0; ms < 4; ++ms)
    #pragma unroll
    for (int r = 0; r < 4; ++r){
      int m = ms * 16 + quad * 4 + r;
      float v0 = gelu_fast(acc1[0][ms][r] + rAv[0] + ca[0][ms * 4 + r]);
      float v1 = gelu_fast(acc1[1][ms][r] + rAv[1] + ca[1][ms * 4 + r]);
      *(unsigned*)&sA[m][swz(m, 128 + w * 32 + c16 * 2)] = f2bf_pk(v0, v1);
    }
  __syncthreads();                                         // B2: gelu1 ready

  // ---- G2: gelu1 @ W1T^T (phi-K) + b1 + raw edge residual ----
  bh8 wb2[2][4];
  #pragma unroll
  for (int t = 0; t < 2; ++t)
    #pragma unroll
    for (int ks = 0; ks < 4; ++ks){
      int col = w * 32 + t * 16 + c16;
      wb2[t][ks] = *(const bh8*)(W1T + (size_t)col * 128 + ks * 32 + quad * 8);
    }
  f32x4 acc2[2][4];
  #pragma unroll
  for (int t = 0; t < 2; ++t) for (int ms = 0; ms < 4; ++ms) acc2[t][ms] = zero4();
  #pragma unroll
  for (int ks = 0; ks < 4; ++ks){
    bh8 af[4];
    #pragma unroll
    for (int ms = 0; ms < 4; ++ms){
      int row = ms * 16 + c16;
      af[ms] = *(const bh8*)&sA[row][swz(row, 128 + ks * 32 + quad * 8)];
    }
    #pragma unroll
    for (int t = 0; t < 2; ++t)
      #pragma unroll
      for (int ms = 0; ms < 4; ++ms)
        acc2[t][ms] = mfma_bf16(af[ms], wb2[t][ks], acc2[t][ms]);
  }
  float b1v[2], g0v[2], b0v[2];
  #pragma unroll
  for (int t = 0; t < 2; ++t){
    int c = w * 32 + t * 16 + c16;
    b1v[t] = b1[c]; g0v[t] = eg0[c]; b0v[t] = eb0[c];
  }
  __syncthreads();                                         // B3a: gelu1 reads done (lr aliases hi)
  // ---- residual + LN0 partials (DPP) -> lr ----
  #pragma unroll
  for (int ms = 0; ms < 4; ++ms)
    #pragma unroll
    for (int r = 0; r < 4; ++r){
      int m = ms * 16 + quad * 4 + r;
      float s = 0.f, q = 0.f;
      #pragma unroll
      for (int t = 0; t < 2; ++t){
        float v = acc2[t][ms][r] + b1v[t] + bf2f(sA[m][swz(m, w * 32 + t * 16 + c16)]);
        acc2[t][ms][r] = v; s += v; q += v * v;
      }
      s = red16_add(s); q = red16_add(q);
      if (c16 == 0){ HIFV(w * 64 + m) = s; HIFV(256 + w * 64 + m) = q; }
    }
  __syncthreads();                                         // B3b: lr ready
  {                                                        // wave w -> stats rows [16w,16w+16)
    int src = lane & 3, mrow = w * 16 + (lane >> 2);
    float sp = HIFV(src * 64 + mrow), qp = HIFV(256 + src * 64 + mrow);
    sp = red4_add(sp); qp = red4_add(qp);
    if (src == 0){
      float mean = sp * (1.f / 128.f);
      float var  = qp * (1.f / 128.f) - mean * mean;
      HIFV(512 + 2 * mrow) = mean;
      HIFV(513 + 2 * mrow) = rsqrtf(var + 1e-5f);
    }
  }
  __syncthreads();                                         // B4a: stats ready
  // ---- LN0 finalize -> edge2 bf16 into lo (paired u32 at position sigma) ----
  #pragma unroll
  for (int ms = 0; ms < 4; ++ms)
    #pragma unroll
    for (int r = 0; r < 4; ++r){
      int m = ms * 16 + quad * 4 + r;
      float2 st = *(float2*)&HIFV(512 + 2 * m);
      float e0 = (acc2[0][ms][r] - st.x) * st.y * g0v[0] + b0v[0];
      float e1 = (acc2[1][ms][r] - st.x) * st.y * g0v[1] + b0v[1];
      *(unsigned*)&sA[m][swz(m, w * 32 + c16 * 2)] = f2bf_pk(e0, e1);
    }
  __syncthreads();                                         // B4b: edge2 ready

  // ---- G3/G4 two-phase over K=256 (hi = gelu3 stage buffer) ----
  f32x4 acc4[2][4];
  #pragma unroll
  for (int t = 0; t < 2; ++t) for (int ms = 0; ms < 4; ++ms) acc4[t][ms] = zero4();
  #pragma unroll
  for (int p = 0; p < 2; ++p){
    bh8 wb3[2][4];
    #pragma unroll
    for (int t = 0; t < 2; ++t)
      #pragma unroll
      for (int ks = 0; ks < 4; ++ks){
        int col = p * 128 + w * 32 + t * 16 + c16;
        wb3[t][ks] = *(const bh8*)(E1W1T + (size_t)col * 128 + ks * 32 + quad * 8);
      }
    f32x4 acc3[2][4];
    #pragma unroll
    for (int t = 0; t < 2; ++t) for (int ms = 0; ms < 4; ++ms) acc3[t][ms] = zero4();
    #pragma unroll
    for (int ks = 0; ks < 4; ++ks){
      bh8 af[4];
      #pragma unroll
      for (int ms = 0; ms < 4; ++ms){
        int row = ms * 16 + c16;
        af[ms] = *(const bh8*)&sA[row][swz(row, ks * 32 + quad * 8)];
      }
      #pragma unroll
      for (int t = 0; t < 2; ++t)
        #pragma unroll
        for (int ms = 0; ms < 4; ++ms)
          acc3[t][ms] = mfma_bf16(af[ms], wb3[t][ks], acc3[t][ms]);
    }
    #pragma unroll
    for (int ms = 0; ms < 4; ++ms)
      #pragma unroll
      for (int r = 0; r < 4; ++r){
        int m = ms * 16 + quad * 4 + r;
        float v0 = gelu_fast(acc3[0][ms][r]);
        float v1 = gelu_fast(acc3[1][ms][r]);
        *(unsigned*)&sA[m][swz(m, 128 + w * 32 + c16 * 2)] = f2bf_pk(v0, v1);
      }
    __syncthreads();                                       // B5: gelu3 phase p ready
    bh8 wb4[2][4];
    #pragma unroll
    for (int t = 0; t < 2; ++t)
      #pragma unroll
      for (int k2 = 0; k2 < 4; ++k2){
        int pcol = w * 32 + c16 * 2 + t;                   // paired output column
        wb4[t][k2] = *(const bh8*)(E1W2T + (size_t)pcol * 256 + p * 128 + k2 * 32 + quad * 8);
      }
    #pragma unroll
    for (int k2 = 0; k2 < 4; ++k2){
      bh8 af[4];
      #pragma unroll
      for (int ms = 0; ms < 4; ++ms){
        int row = ms * 16 + c16;
        af[ms] = *(const bh8*)&sA[row][swz(row, 128 + k2 * 32 + quad * 8)];
      }
      #pragma unroll
      for (int t = 0; t < 2; ++t)
        #pragma unroll
        for (int ms = 0; ms < 4; ++ms)
          acc4[t][ms] = mfma_bf16(af[ms], wb4[t][k2], acc4[t][ms]);
    }
    __syncthreads();                                       // B6: hi reads done
  }

  // ---- G4 epilogue: + b2 + edge2 residual -> LN1 (DPP) -> full-line store ----
  float b2v[2], g1v[2], bb1v[2]; int slv[2];
  #pragma unroll
  for (int t = 0; t < 2; ++t){
    int pcol = w * 32 + c16 * 2 + t;
    b2v[t] = e1b2[pcol]; g1v[t] = eg1[pcol]; bb1v[t] = eb1[pcol];
    int lo5 = c16 * 2 + t;
    slv[t] = w * 32 + (((lo5 & 15) << 1) | (lo5 >> 4));    // sigma(pcol): edge2 storage position
  }
  #pragma unroll
  for (int ms = 0; ms < 4; ++ms)
    #pragma unroll
    for (int r = 0; r < 4; ++r){
      int m = ms * 16 + quad * 4 + r;
      float s = 0.f, q = 0.f;
      #pragma unroll
      for (int t = 0; t < 2; ++t){
        float v = acc4[t][ms][r] + b2v[t] + bf2f(sA[m][swz(m, slv[t])]);
        acc4[t][ms][r] = v; s += v; q += v * v;
      }
      s = red16_add(s); q = red16_add(q);
      if (c16 == 0){ HIFV(w * 64 + m) = s; HIFV(256 + w * 64 + m) = q; }
    }
  __syncthreads();                                         // B9: lr ready
  {
    int src = lane & 3, mrow = w * 16 + (lane >> 2);
    float sp = HIFV(src * 64 + mrow), qp = HIFV(256 + src * 64 + mrow);
    sp = red4_add(sp); qp = red4_add(qp);
    if (src == 0){
      float mean = sp * (1.f / 128.f);
      float var  = qp * (1.f / 128.f) - mean * mean;
      HIFV(512 + 2 * mrow) = mean;
      HIFV(513 + 2 * mrow) = rsqrtf(var + 1e-5f);
    }
  }
  __syncthreads();                                         // B10: stats ready
  float* outBase = eOut + ((size_t)(b * N_ + i) * N_ + j0) * D_;
  #pragma unroll
  for (int ms = 0; ms < 4; ++ms)
    #pragma unroll
    for (int r = 0; r < 4; ++r){
      int m = ms * 16 + quad * 4 + r;
      float2 st = *(float2*)&HIFV(512 + 2 * m);
      float2 ov;
      ov.x = (acc4[0][ms][r] - st.x) * st.y * g1v[0] + bb1v[0];
      ov.y = (acc4[1][ms][r] - st.x) * st.y * g1v[1] + bb1v[1];
      *(float2*)&outBase[(size_t)m * D_ + w * 32 + c16 * 2] = ov;   // 128B line per row per instr
    }
#undef HIFV
}

extern "C" void kernel_launch(void* const* d_in, const int* in_sizes, int n_in,
                              void* d_out, int out_size, void* d_ws, size_t ws_size,
                              hipStream_t stream){
  const float* node   = (const float*)d_in[0];
  const float* edge   = (const float*)d_in[1];
  const float* wqkv_n = (const float*)d_in[3];
  const float* wqkv_e = (const float*)d_in[4];
  const float* lin0_w = (const float*)d_in[5];
  const float* lin0_b = (const float*)d_in[6];
  const float* ln0_g  = (const float*)d_in[7];
  const float* ln0_b  = (const float*)d_in[8];
  const float* ln1_g  = (const float*)d_in[9];
  const float* ln1_b  = (const float*)d_in[10];
  const float* nmlp_w1= (const float*)d_in[11];
  const float* nmlp_w2= (const float*)d_in[12];
  const float* nmlp_b2= (const float*)d_in[13];
  const float* e0_we  = (const float*)d_in[14];
  const float* e0_be  = (const float*)d_in[15];
  const float* e0_ws  = (const float*)d_in[16];
  const float* e0_bs  = (const float*)d_in[17];
  const float* e0_wt  = (const float*)d_in[18];
  const float* e0_bt  = (const float*)d_in[19];
  const float* e0_wer = (const float*)d_in[20];
  const float* e0_wec = (const float*)d_in[21];
  const float* e0_w1  = (const float*)d_in[22];
  const float* e0_b1  = (const float*)d_in[23];
  const float* e1_w1  = (const float*)d_in[24];
  const float* e1_w2  = (const float*)d_in[25];
  const float* e1_b2  = (const float*)d_in[26];
  const float* eln0_g = (const float*)d_in[27];
  const float* eln0_b = (const float*)d_in[28];
  const float* eln1_g = (const float*)d_in[29];
  const float* eln1_b = (const float*)d_in[30];

  unsigned short* E16   = (unsigned short*)d_ws;
  unsigned short* WqkvT = E16 + (size_t)EDGE_ELEMS;
  unsigned short* WeT   = WqkvT + 65536;
  unsigned short* W1T   = WeT + 32768;
  unsigned short* E1W1T = W1T + 16384;
  unsigned short* E1W2T = E1W1T + 32768;
  float* fbase  = (float*)(E1W2T + 32768);
  float* qkvn   = fbase;
  float* attn   = qkvn + (size_t)BN * 384;
  float* meanJ  = attn + NODE_ELEMS;
  float* meanI  = meanJ + NODE_ELEMS;
  float* rowAdd = meanI + NODE_ELEMS;
  float* colAdd = rowAdd + NODE_ELEMS;

  float* xOut = (float*)d_out;
  float* eOut = xOut + NODE_ELEMS;

  kprep<<<dim3(BN, 6), 384, 0, stream>>>(wqkv_e, e0_we, e0_w1, e1_w1, e1_w2,
                                         node, wqkv_n,
                                         WqkvT, WeT, W1T, E1W1T, E1W2T, qkvn);
  kprepA<<<BN, 256, 0, stream>>>(edge, E16, meanJ);
  kattnI<<<dim3(BN, 2), 256, 0, stream>>>(E16, WqkvT, qkvn, attn, meanI);
  knodeadd<<<BN, 256, 0, stream>>>(node, attn, lin0_w, lin0_b, ln0_g, ln0_b,
                                   nmlp_w1, nmlp_w2, nmlp_b2, ln1_g, ln1_b,
                                   meanJ, meanI, e0_ws, e0_bs, e0_wt, e0_bt,
                                   e0_wer, e0_wec, e0_be,
                                   xOut, rowAdd, colAdd);
  const int HALF = NN * B_ / 64 / 2;   // 1152
  kedge4<<<HALF, 256, 0, stream>>>(E16, WeT, W1T, E1W1T, E1W2T,
                                   rowAdd, colAdd, e0_b1,
                                   eln0_g, eln0_b, e1_b2, eln1_g, eln1_b,
                                   eOut, 0);
  kedge4<<<HALF, 256, 0, stream>>>(E16, WeT, W1T, E1W1T, E1W2T,
                                   rowAdd, colAdd, e0_b1,
                                   eln0_g, eln0_b, e1_b2, eln1_g, eln1_b,
                                   eOut, HALF);
}

// Round 8
// 623.606 us; speedup vs baseline: 1.2863x; 1.0127x over previous
//
#include <hip/hip_runtime.h>
#include <hip/hip_bf16.h>
#include <cstdint>
#include <cstddef>

#define B_ 2
#define N_ 384
#define D_ 128
#define NN (N_*N_)                  // 147456
#define BN (B_*N_)                  // 768
#define EDGE_ELEMS (B_*NN*D_)       // 37748736
#define NODE_ELEMS (BN*D_)          // 98304

typedef short bh8 __attribute__((ext_vector_type(8)));
typedef float f32x4 __attribute__((ext_vector_type(4)));

__device__ __forceinline__ f32x4 mfma_bf16(bh8 a, bh8 b, f32x4 c){
  return __builtin_amdgcn_mfma_f32_16x16x32_bf16(a, b, c, 0, 0, 0);
}
__device__ __forceinline__ unsigned short f2bf(float f){
  unsigned u = __float_as_uint(f);
  return (unsigned short)((u + 0x7fffu + ((u >> 16) & 1u)) >> 16);
}
__device__ __forceinline__ unsigned f2bf_pk(float a, float b){   // packed cvt: lo=a, hi=b
  __hip_bfloat162 h = __float22bfloat162_rn(make_float2(a, b));
  return *(unsigned*)&h;
}
__device__ __forceinline__ float bf2f(unsigned short h){
  return __uint_as_float(((unsigned)h) << 16);
}
__device__ __forceinline__ float geluf(float x){        // exact (node path)
  return 0.5f * x * (1.0f + erff(x * 0.70710678118654752f));
}
__device__ __forceinline__ float gelu_fast(float x){    // tanh approx via hw exp
  float x2 = x * x;
  float t  = __fmaf_rn(0.044715f * x, x2, x);
  float e  = __expf(1.5957691216057308f * t);
  float r  = __builtin_amdgcn_rcpf(e + 1.0f);
  return x - x * r;
}
__device__ __forceinline__ f32x4 zero4(){ f32x4 z = {0.f,0.f,0.f,0.f}; return z; }

// ---- DPP reductions (VALU pipe) ----
__device__ __forceinline__ float red16_add(float x){
  x += __int_as_float(__builtin_amdgcn_update_dpp(0, __float_as_int(x), 0xB1, 0xF, 0xF, true));  // quad_perm [1,0,3,2]
  x += __int_as_float(__builtin_amdgcn_update_dpp(0, __float_as_int(x), 0x4E, 0xF, 0xF, true));  // quad_perm [2,3,0,1]
  x += __int_as_float(__builtin_amdgcn_update_dpp(0, __float_as_int(x), 0x141, 0xF, 0xF, true)); // row_half_mirror
  x += __int_as_float(__builtin_amdgcn_update_dpp(0, __float_as_int(x), 0x140, 0xF, 0xF, true)); // row_mirror
  return x;
}
__device__ __forceinline__ float red4_add(float x){
  x += __int_as_float(__builtin_amdgcn_update_dpp(0, __float_as_int(x), 0xB1, 0xF, 0xF, true));
  x += __int_as_float(__builtin_amdgcn_update_dpp(0, __float_as_int(x), 0x4E, 0xF, 0xF, true));
  return x;
}
// XOR chunk swizzle: logical (row m, short-pos p in 0..255) -> physical short index.
__device__ __forceinline__ int swz(int m, int p){
  return ((((p >> 3) ^ (m & 7)) << 3) | (p & 7));
}
// channel-pairing permutation: position p holds channel phi(p) (rotate-right of low 5 bits);
// storage position of channel c is sigma(c) = rotate-left of low 5 bits.
__device__ __forceinline__ int PHIDX(int x){   // x < 128
  return (x & ~31) | ((x & 1) << 4) | ((x & 31) >> 1);
}

// ------- merged prep: y<5 weight bf16-transpose (phi-K), y==5 node qkv GEMV,
//         y==6 edge fp32->bf16 + meanJ (former kprepA; 384 thr, 32 iters/row) -------
__global__ void kprep(const float* wqkv_e, const float* e0_we, const float* e0_w1,
                      const float* e1_w1, const float* e1_w2,
                      const float* node, const float* wqkv_n,
                      const float* __restrict__ edge,
                      unsigned short* WqkvT, unsigned short* WeT, unsigned short* W1T,
                      unsigned short* E1W1T, unsigned short* E1W2T,
                      float* qkvn, unsigned short* __restrict__ E16,
                      float* __restrict__ meanJ){
  int m = blockIdx.y;
  int tid = threadIdx.x;
  if (m < 5){
    const float* src; unsigned short* dst; int K, Nn;
    if (m == 0){ src = wqkv_e; dst = WqkvT; K = 128; Nn = 512; }
    else if (m == 1){ src = e0_we; dst = WeT;   K = 256; Nn = 128; }
    else if (m == 2){ src = e0_w1; dst = W1T;   K = 128; Nn = 128; }
    else if (m == 3){ src = e1_w1; dst = E1W1T; K = 128; Nn = 256; }
    else            { src = e1_w2; dst = E1W2T; K = 256; Nn = 128; }
    int idx = blockIdx.x * 384 + tid;
    if (idx < K * Nn){
      int n = idx / K, k = idx % K;
      int ksrc = (m >= 2) ? ((k & ~127) | PHIDX(k & 127)) : k;  // bake channel-pair perm into K
      dst[idx] = f2bf(src[ksrc * Nn + n]);
    }
  } else if (m == 5){
    int row = blockIdx.x;
    __shared__ float sn[128];
    if (tid < 128) sn[tid] = node[row * 128 + tid];
    __syncthreads();
    float acc = 0.f;
    #pragma unroll 8
    for (int k = 0; k < 128; ++k) acc += sn[k] * wqkv_n[k * 384 + tid];
    qkvn[row * 384 + tid] = acc;
  } else {
    // ---- edge fp32 -> bf16 + meanJ, 384 threads, 32 iterations ----
    __shared__ float red[12][128];
    int bi = blockIdx.x;
    const float4* src = (const float4*)(edge + (size_t)bi * N_ * D_);
    uint2* gdst = (uint2*)E16 + (size_t)bi * (N_ * D_ / 4);
    float ps0 = 0.f, ps1 = 0.f, ps2 = 0.f, ps3 = 0.f;
    #pragma unroll 4
    for (int k = 0; k < 32; ++k){
      int idx = k * 384 + tid;
      float4 v = src[idx];
      uint2 o;
      o.x = f2bf_pk(v.x, v.y);
      o.y = f2bf_pk(v.z, v.w);
      gdst[idx] = o;
      ps0 += v.x; ps1 += v.y; ps2 += v.z; ps3 += v.w;
    }
    int g = tid >> 5, d0 = (tid & 31) * 4;
    red[g][d0] = ps0; red[g][d0 + 1] = ps1; red[g][d0 + 2] = ps2; red[g][d0 + 3] = ps3;
    __syncthreads();
    if (tid < 128){
      float s = 0.f;
      #pragma unroll
      for (int gg = 0; gg < 12; ++gg) s += red[gg][tid];
      meanJ[bi * 128 + tid] = s * (1.0f / N_);
    }
  }
}

// ---- merged: y==0 attention (2 heads/wave, prefetch), y==1 meanI column pass ----
__global__ __launch_bounds__(256, 2) void kattnI(
    const unsigned short* __restrict__ E16, const unsigned short* __restrict__ WqkvT,
    const float* __restrict__ qkvn, float* __restrict__ attn,
    float* __restrict__ meanI){
  __shared__ float red[16][128];
  int tid = threadIdx.x;
  if (blockIdx.y == 1){
    int bj = blockIdx.x; int b = bj / N_, j = bj % N_;
    int ig = tid >> 4, dsub = tid & 15;
    float acc[8];
    #pragma unroll
    for (int e = 0; e < 8; ++e) acc[e] = 0.f;
    #pragma unroll 4
    for (int i = ig; i < N_; i += 16){
      const unsigned short* p = E16 + ((size_t)(b * N_ + i) * N_ + j) * D_ + dsub * 8;
      uint4 u = *(const uint4*)p;
      acc[0] += bf2f((unsigned short)(u.x & 0xffff)); acc[1] += bf2f((unsigned short)(u.x >> 16));
      acc[2] += bf2f((unsigned short)(u.y & 0xffff)); acc[3] += bf2f((unsigned short)(u.y >> 16));
      acc[4] += bf2f((unsigned short)(u.z & 0xffff)); acc[5] += bf2f((unsigned short)(u.z >> 16));
      acc[6] += bf2f((unsigned short)(u.w & 0xffff)); acc[7] += bf2f((unsigned short)(u.w >> 16));
    }
    #pragma unroll
    for (int e = 0; e < 8; ++e) red[ig][dsub * 8 + e] = acc[e];
    __syncthreads();
    if (tid < 128){
      float s = 0.f;
      #pragma unroll
      for (int gg = 0; gg < 16; ++gg) s += red[gg][tid];
      meanI[bj * 128 + tid] = s * (1.0f / N_);
    }
    return;
  }
  int bi = blockIdx.x; int b = bi / N_;
  int w = tid >> 6, lane = tid & 63, quad = lane >> 4, c16 = lane & 15;
  const float scale = 0.08838834764831845f;   // 1/sqrt(128)
  const unsigned short* Abase = E16 + (size_t)bi * N_ * D_;

  bh8 bf[2][4][4];
  #pragma unroll
  for (int s = 0; s < 2; ++s){
    int h = w + s * 4;
    #pragma unroll
    for (int u = 0; u < 4; ++u)
      #pragma unroll
      for (int ks = 0; ks < 4; ++ks){
        int col = h * 64 + u * 16 + c16;
        bf[s][u][ks] = *(const bh8*)(WqkvT + col * 128 + ks * 32 + quad * 8);
      }
  }
  float qv[2];
  #pragma unroll
  for (int s = 0; s < 2; ++s) qv[s] = qkvn[bi * 384 + (w + s * 4) * 48 + c16];

  float m_run[2] = {-1e30f, -1e30f}, l_run[2] = {0.f, 0.f}, o[2] = {0.f, 0.f};
  bh8 af[4];
  #pragma unroll
  for (int ks = 0; ks < 4; ++ks)
    af[ks] = *(const bh8*)(Abase + (size_t)c16 * D_ + ks * 32 + quad * 8);

  for (int jt = 0; jt < 24; ++jt){
    int jn = (jt + 1 < 24) ? jt + 1 : 0;
    bh8 afn[4];
    #pragma unroll
    for (int ks = 0; ks < 4; ++ks)
      afn[ks] = *(const bh8*)(Abase + (size_t)(jn * 16 + c16) * D_ + ks * 32 + quad * 8);
    float knv[2][4], vnv[2][4];
    const float* kvb = qkvn + ((size_t)b * N_ + jt * 16 + quad * 4) * 384;
    #pragma unroll
    for (int s = 0; s < 2; ++s)
      #pragma unroll
      for (int r = 0; r < 4; ++r){
        knv[s][r] = kvb[r * 384 + (w + s * 4) * 48 + 16 + c16];
        vnv[s][r] = kvb[r * 384 + (w + s * 4) * 48 + 32 + c16];
      }
    f32x4 EQ[2], EK[2], EV[2], EM[2];
    #pragma unroll
    for (int s = 0; s < 2; ++s){ EQ[s] = zero4(); EK[s] = zero4(); EV[s] = zero4(); EM[s] = zero4(); }
    #pragma unroll
    for (int ks = 0; ks < 4; ++ks)
      #pragma unroll
      for (int s = 0; s < 2; ++s){
        EQ[s] = mfma_bf16(af[ks], bf[s][0][ks], EQ[s]);
        EK[s] = mfma_bf16(af[ks], bf[s][1][ks], EK[s]);
        EV[s] = mfma_bf16(af[ks], bf[s][2][ks], EV[s]);
        EM[s] = mfma_bf16(af[ks], bf[s][3][ks], EM[s]);
      }
    #pragma unroll
    for (int s = 0; s < 2; ++s){
      float dots[4], vv[4];
      #pragma unroll
      for (int r = 0; r < 4; ++r){
        float t1 = (qv[s] + EQ[s][r]) * (knv[s][r] + EK[s][r]);
        dots[r] = red16_add(t1) * scale;
        vv[r] = vnv[s][r] * EM[s][r] + EV[s][r];
      }
      float tmax = fmaxf(fmaxf(dots[0], dots[1]), fmaxf(dots[2], dots[3]));
      tmax = fmaxf(tmax, __shfl_xor(tmax, 16));
      tmax = fmaxf(tmax, __shfl_xor(tmax, 32));
      float mnew = fmaxf(m_run[s], tmax);
      float al = __expf(m_run[s] - mnew);
      float p0 = __expf(dots[0] - mnew), p1 = __expf(dots[1] - mnew);
      float p2 = __expf(dots[2] - mnew), p3 = __expf(dots[3] - mnew);
      float lt = p0 + p1 + p2 + p3;
      lt += __shfl_xor(lt, 16); lt += __shfl_xor(lt, 32);
      l_run[s] = l_run[s] * al + lt;
      m_run[s] = mnew;
      o[s] = o[s] * al + p0 * vv[0] + p1 * vv[1] + p2 * vv[2] + p3 * vv[3];
    }
    #pragma unroll
    for (int ks = 0; ks < 4; ++ks) af[ks] = afn[ks];
  }
  #pragma unroll
  for (int s = 0; s < 2; ++s){
    float oo = o[s];
    oo += __shfl_xor(oo, 16); oo += __shfl_xor(oo, 32);
    oo /= l_run[s];
    if (quad == 0) attn[(size_t)bi * D_ + (w + s * 4) * 16 + c16] = oo;
  }
}

// -------- node path v2: TWO rows per block (full lane utilization).
//   tid<128 owns row 2b, tid>=128 owns row 2b+1. LN reductions are wave-aligned
//   (128 lanes = 2 waves per row). w1 phase: each thread does 2 of its row's 256.
__global__ void knodeadd(const float* __restrict__ node, const float* __restrict__ attn,
                         const float* lin0_w, const float* lin0_b,
                         const float* g0, const float* bb0,
                         const float* w1, const float* w2, const float* b2,
                         const float* g1, const float* bb1,
                         const float* __restrict__ meanJ, const float* __restrict__ meanI,
                         const float* ws, const float* bs, const float* wt, const float* bt,
                         const float* wer, const float* wec, const float* be,
                         float* __restrict__ xOut,
                         float* __restrict__ rowAdd, float* __restrict__ colAdd){
  int tid = threadIdx.x;
  int h = tid >> 7, lid = tid & 127;           // h: which row of the pair
  int row = blockIdx.x * 2 + h;
  __shared__ float sa[2][128], sx[2][128], sh[2][256], rb[8], sx2[2][128], smJ[2][128], smI[2][128];
  sa[h][lid]  = attn[row * 128 + lid];
  smJ[h][lid] = meanJ[row * 128 + lid];
  smI[h][lid] = meanI[row * 128 + lid];
  __syncthreads();
  // ---- lin0 + residual ----
  float y, x0;
  {
    float acc = lin0_b[lid];
    #pragma unroll 8
    for (int k = 0; k < 128; ++k) acc += sa[h][k] * lin0_w[k * 128 + lid];
    y = acc + node[row * 128 + lid];
  }
  { float sv = y, sq = y * y;
    sv = red16_add(sv); sq = red16_add(sq);
    sv += __shfl_xor(sv, 16); sq += __shfl_xor(sq, 16);
    sv += __shfl_xor(sv, 32); sq += __shfl_xor(sq, 32);
    if ((tid & 63) == 0){ rb[tid >> 6] = sv; rb[4 + (tid >> 6)] = sq; } }
  __syncthreads();
  float mean = (rb[h * 2] + rb[h * 2 + 1]) * (1.f / 128.f);
  float var  = (rb[4 + h * 2] + rb[4 + h * 2 + 1]) * (1.f / 128.f) - mean * mean;
  float rstd = rsqrtf(var + 1e-5f);
  x0 = (y - mean) * rstd * g0[lid] + bb0[lid];
  sx[h][lid] = x0;
  __syncthreads();
  // ---- MLP w1 (256-wide): 2 outputs per thread ----
  #pragma unroll
  for (int u = 0; u < 2; ++u){
    int e = lid + u * 128;
    float acc = 0.f;
    #pragma unroll 8
    for (int k = 0; k < 128; ++k) acc += sx[h][k] * w1[k * 256 + e];
    sh[h][e] = geluf(acc);
  }
  __syncthreads();
  // ---- MLP w2 + residual ----
  float y2;
  {
    float acc = b2[lid];
    #pragma unroll 8
    for (int e = 0; e < 256; ++e) acc += sh[h][e] * w2[e * 128 + lid];
    y2 = acc + x0;
  }
  { float sv = y2, sq = y2 * y2;
    sv = red16_add(sv); sq = red16_add(sq);
    sv += __shfl_xor(sv, 16); sq += __shfl_xor(sq, 16);
    sv += __shfl_xor(sv, 32); sq += __shfl_xor(sq, 32);
    if ((tid & 63) == 0){ rb[tid >> 6] = sv; rb[4 + (tid >> 6)] = sq; } }
  __syncthreads();
  mean = (rb[h * 2] + rb[h * 2 + 1]) * (1.f / 128.f);
  var  = (rb[4 + h * 2] + rb[4 + h * 2 + 1]) * (1.f / 128.f) - mean * mean;
  rstd = rsqrtf(var + 1e-5f);
  {
    float xv = (y2 - mean) * rstd * g1[lid] + bb1[lid];
    xOut[row * 128 + lid] = xv;
    sx2[h][lid] = xv;
  }
  __syncthreads();
  // ---- addends: loop rows; tid<128 -> rowAdd (ws,wer), tid>=128 -> colAdd (wt,wec) ----
  #pragma unroll
  for (int rr = 0; rr < 2; ++rr){
    int orow = blockIdx.x * 2 + rr;
    int d = lid;
    if (tid < 128){
      float s1 = bs[d], s3 = 0.f;
      #pragma unroll 8
      for (int k = 0; k < 128; ++k){
        s1 += sx2[rr][k] * ws[k * 128 + d];
        s3 += smJ[rr][k] * wer[k * 128 + d];
      }
      rowAdd[orow * 128 + d] = s1 + s3 + be[d];
    } else {
      float s2 = bt[d], s4 = 0.f;
      #pragma unroll 8
      for (int k = 0; k < 128; ++k){
        s2 += sx2[rr][k] * wt[k * 128 + d];
        s4 += smI[rr][k] * wec[k * 128 + d];
      }
      colAdd[orow * 128 + d] = s2 + s4;
    }
  }
}

// -- fused edge pipeline v10 (single dispatch): v8 body, 32 KiB aliased LDS,
//    paired-channel u32 LDS writes, full-line float2 stores, (256,3) no-spill.
__global__ __launch_bounds__(256, 3) void kedge4(
    const unsigned short* __restrict__ E16, const unsigned short* __restrict__ WeT,
    const unsigned short* __restrict__ W1T, const unsigned short* __restrict__ E1W1T,
    const unsigned short* __restrict__ E1W2T,
    const float* __restrict__ rowAdd, const float* __restrict__ colAdd,
    const float* __restrict__ b1, const float* __restrict__ eg0, const float* __restrict__ eb0,
    const float* __restrict__ e1b2, const float* __restrict__ eg1, const float* __restrict__ eb1,
    float* __restrict__ eOut){
  __shared__ unsigned short sA[64][256];   // lo (p<128): K0-127 / edge2; hi (p>=128): K128-255 / stage buf
#define HIFV(i) (((float*)&sA[0][0])[ (((i) >> 6) << 7) + 64 + ((i) & 63) ])  // hi-half float alias
  int tid = threadIdx.x;
  int w = tid >> 6, lane = tid & 63, quad = lane >> 4, c16 = lane & 15;
  int R0 = blockIdx.x * 64;
  int b = R0 / NN; int rem = R0 % NN; int i = rem / N_; int j0 = rem % N_;

  // ---- prefetch G1 weights ----
  bh8 wb1[2][8];
  #pragma unroll
  for (int t = 0; t < 2; ++t)
    #pragma unroll
    for (int ks = 0; ks < 8; ++ks){
      int col = w * 32 + t * 16 + c16;
      wb1[t][ks] = *(const bh8*)(WeT + (size_t)col * 256 + ks * 32 + quad * 8);
    }

  // ---- stage A = [edge(b,i,j0+m,:) | edge(b,j0+m,i,:)] bf16, 64x256, chunk-XOR ----
  #pragma unroll
  for (int it = 0; it < 8; ++it){
    int cid = it * 256 + tid;
    int rrow = cid >> 5;
    int chunk = cid & 31;
    int kc = chunk * 8;
    const unsigned short* sp;
    if (kc < 128) sp = E16 + ((size_t)(b * N_ + i) * N_ + (j0 + rrow)) * D_ + kc;
    else          sp = E16 + ((size_t)(b * N_ + j0 + rrow) * N_ + i) * D_ + (kc - 128);
    *(float4*)&sA[rrow][(chunk ^ (rrow & 7)) << 3] = *(const float4*)sp;
  }
  __syncthreads();                                         // B1: staged

  // ---- G1 k-loop: A(64x256) @ WeT^T -> cols [32w,32w+32) ----
  f32x4 acc1[2][4];
  #pragma unroll
  for (int t = 0; t < 2; ++t) for (int ms = 0; ms < 4; ++ms) acc1[t][ms] = zero4();
  #pragma unroll
  for (int ks = 0; ks < 8; ++ks){
    bh8 af[4];
    #pragma unroll
    for (int ms = 0; ms < 4; ++ms){
      int row = ms * 16 + c16;
      af[ms] = *(const bh8*)&sA[row][swz(row, ks * 32 + quad * 8)];
    }
    #pragma unroll
    for (int t = 0; t < 2; ++t)
      #pragma unroll
      for (int ms = 0; ms < 4; ++ms)
        acc1[t][ms] = mfma_bf16(af[ms], wb1[t][ks], acc1[t][ms]);
  }
  // addends (short live range; latency hidden by B1.5 wait)
  float rAv[2], ca[2][16];
  #pragma unroll
  for (int t = 0; t < 2; ++t){
    rAv[t] = rowAdd[(b * N_ + i) * D_ + w * 32 + t * 16 + c16];
    #pragma unroll
    for (int ms = 0; ms < 4; ++ms)
      #pragma unroll
      for (int r = 0; r < 4; ++r)
        ca[t][ms * 4 + r] = colAdd[(size_t)(b * N_ + j0 + ms * 16 + quad * 4 + r) * D_
                                   + w * 32 + t * 16 + c16];
  }
  __syncthreads();                                         // B1.5: all hi-K reads done

  // ---- gelu1 -> hi (paired u32 at position sigma) ----
  #pragma unroll
  for (int ms = 0; ms < 4; ++ms)
    #pragma unroll
    for (int r = 0; r < 4; ++r){
      int m = ms * 16 + quad * 4 + r;
      float v0 = gelu_fast(acc1[0][ms][r] + rAv[0] + ca[0][ms * 4 + r]);
      float v1 = gelu_fast(acc1[1][ms][r] + rAv[1] + ca[1][ms * 4 + r]);
      *(unsigned*)&sA[m][swz(m, 128 + w * 32 + c16 * 2)] = f2bf_pk(v0, v1);
    }
  __syncthreads();                                         // B2: gelu1 ready

  // ---- G2: gelu1 @ W1T^T (phi-K) + b1 + raw edge residual ----
  bh8 wb2[2][4];
  #pragma unroll
  for (int t = 0; t < 2; ++t)
    #pragma unroll
    for (int ks = 0; ks < 4; ++ks){
      int col = w * 32 + t * 16 + c16;
      wb2[t][ks] = *(const bh8*)(W1T + (size_t)col * 128 + ks * 32 + quad * 8);
    }
  f32x4 acc2[2][4];
  #pragma unroll
  for (int t = 0; t < 2; ++t) for (int ms = 0; ms < 4; ++ms) acc2[t][ms] = zero4();
  #pragma unroll
  for (int ks = 0; ks < 4; ++ks){
    bh8 af[4];
    #pragma unroll
    for (int ms = 0; ms < 4; ++ms){
      int row = ms * 16 + c16;
      af[ms] = *(const bh8*)&sA[row][swz(row, 128 + ks * 32 + quad * 8)];
    }
    #pragma unroll
    for (int t = 0; t < 2; ++t)
      #pragma unroll
      for (int ms = 0; ms < 4; ++ms)
        acc2[t][ms] = mfma_bf16(af[ms], wb2[t][ks], acc2[t][ms]);
  }
  float b1v[2], g0v[2], b0v[2];
  #pragma unroll
  for (int t = 0; t < 2; ++t){
    int c = w * 32 + t * 16 + c16;
    b1v[t] = b1[c]; g0v[t] = eg0[c]; b0v[t] = eb0[c];
  }
  __syncthreads();                                         // B3a: gelu1 reads done (lr aliases hi)
  // ---- residual + LN0 partials (DPP) -> lr ----
  #pragma unroll
  for (int ms = 0; ms < 4; ++ms)
    #pragma unroll
    for (int r = 0; r < 4; ++r){
      int m = ms * 16 + quad * 4 + r;
      float s = 0.f, q = 0.f;
      #pragma unroll
      for (int t = 0; t < 2; ++t){
        float v = acc2[t][ms][r] + b1v[t] + bf2f(sA[m][swz(m, w * 32 + t * 16 + c16)]);
        acc2[t][ms][r] = v; s += v; q += v * v;
      }
      s = red16_add(s); q = red16_add(q);
      if (c16 == 0){ HIFV(w * 64 + m) = s; HIFV(256 + w * 64 + m) = q; }
    }
  __syncthreads();                                         // B3b: lr ready
  {                                                        // wave w -> stats rows [16w,16w+16)
    int src = lane & 3, mrow = w * 16 + (lane >> 2);
    float sp = HIFV(src * 64 + mrow), qp = HIFV(256 + src * 64 + mrow);
    sp = red4_add(sp); qp = red4_add(qp);
    if (src == 0){
      float mean = sp * (1.f / 128.f);
      float var  = qp * (1.f / 128.f) - mean * mean;
      HIFV(512 + 2 * mrow) = mean;
      HIFV(513 + 2 * mrow) = rsqrtf(var + 1e-5f);
    }
  }
  __syncthreads();                                         // B4a: stats ready
  // ---- LN0 finalize -> edge2 bf16 into lo (paired u32 at position sigma) ----
  #pragma unroll
  for (int ms = 0; ms < 4; ++ms)
    #pragma unroll
    for (int r = 0; r < 4; ++r){
      int m = ms * 16 + quad * 4 + r;
      float2 st = *(float2*)&HIFV(512 + 2 * m);
      float e0 = (acc2[0][ms][r] - st.x) * st.y * g0v[0] + b0v[0];
      float e1 = (acc2[1][ms][r] - st.x) * st.y * g0v[1] + b0v[1];
      *(unsigned*)&sA[m][swz(m, w * 32 + c16 * 2)] = f2bf_pk(e0, e1);
    }
  __syncthreads();                                         // B4b: edge2 ready

  // ---- G3/G4 two-phase over K=256 (hi = gelu3 stage buffer) ----
  f32x4 acc4[2][4];
  #pragma unroll
  for (int t = 0; t < 2; ++t) for (int ms = 0; ms < 4; ++ms) acc4[t][ms] = zero4();
  #pragma unroll
  for (int p = 0; p < 2; ++p){
    bh8 wb3[2][4];
    #pragma unroll
    for (int t = 0; t < 2; ++t)
      #pragma unroll
      for (int ks = 0; ks < 4; ++ks){
        int col = p * 128 + w * 32 + t * 16 + c16;
        wb3[t][ks] = *(const bh8*)(E1W1T + (size_t)col * 128 + ks * 32 + quad * 8);
      }
    f32x4 acc3[2][4];
    #pragma unroll
    for (int t = 0; t < 2; ++t) for (int ms = 0; ms < 4; ++ms) acc3[t][ms] = zero4();
    #pragma unroll
    for (int ks = 0; ks < 4; ++ks){
      bh8 af[4];
      #pragma unroll
      for (int ms = 0; ms < 4; ++ms){
        int row = ms * 16 + c16;
        af[ms] = *(const bh8*)&sA[row][swz(row, ks * 32 + quad * 8)];
      }
      #pragma unroll
      for (int t = 0; t < 2; ++t)
        #pragma unroll
        for (int ms = 0; ms < 4; ++ms)
          acc3[t][ms] = mfma_bf16(af[ms], wb3[t][ks], acc3[t][ms]);
    }
    #pragma unroll
    for (int ms = 0; ms < 4; ++ms)
      #pragma unroll
      for (int r = 0; r < 4; ++r){
        int m = ms * 16 + quad * 4 + r;
        float v0 = gelu_fast(acc3[0][ms][r]);
        float v1 = gelu_fast(acc3[1][ms][r]);
        *(unsigned*)&sA[m][swz(m, 128 + w * 32 + c16 * 2)] = f2bf_pk(v0, v1);
      }
    __syncthreads();                                       // B5: gelu3 phase p ready
    bh8 wb4[2][4];
    #pragma unroll
    for (int t = 0; t < 2; ++t)
      #pragma unroll
      for (int k2 = 0; k2 < 4; ++k2){
        int pcol = w * 32 + c16 * 2 + t;                   // paired output column
        wb4[t][k2] = *(const bh8*)(E1W2T + (size_t)pcol * 256 + p * 128 + k2 * 32 + quad * 8);
      }
    #pragma unroll
    for (int k2 = 0; k2 < 4; ++k2){
      bh8 af[4];
      #pragma unroll
      for (int ms = 0; ms < 4; ++ms){
        int row = ms * 16 + c16;
        af[ms] = *(const bh8*)&sA[row][swz(row, 128 + k2 * 32 + quad * 8)];
      }
      #pragma unroll
      for (int t = 0; t < 2; ++t)
        #pragma unroll
        for (int ms = 0; ms < 4; ++ms)
          acc4[t][ms] = mfma_bf16(af[ms], wb4[t][k2], acc4[t][ms]);
    }
    __syncthreads();                                       // B6: hi reads done
  }

  // ---- G4 epilogue: + b2 + edge2 residual -> LN1 (DPP) -> full-line store ----
  float b2v[2], g1v[2], bb1v[2]; int slv[2];
  #pragma unroll
  for (int t = 0; t < 2; ++t){
    int pcol = w * 32 + c16 * 2 + t;
    b2v[t] = e1b2[pcol]; g1v[t] = eg1[pcol]; bb1v[t] = eb1[pcol];
    int lo5 = c16 * 2 + t;
    slv[t] = w * 32 + (((lo5 & 15) << 1) | (lo5 >> 4));    // sigma(pcol): edge2 storage position
  }
  #pragma unroll
  for (int ms = 0; ms < 4; ++ms)
    #pragma unroll
    for (int r = 0; r < 4; ++r){
      int m = ms * 16 + quad * 4 + r;
      float s = 0.f, q = 0.f;
      #pragma unroll
      for (int t = 0; t < 2; ++t){
        float v = acc4[t][ms][r] + b2v[t] + bf2f(sA[m][swz(m, slv[t])]);
        acc4[t][ms][r] = v; s += v; q += v * v;
      }
      s = red16_add(s); q = red16_add(q);
      if (c16 == 0){ HIFV(w * 64 + m) = s; HIFV(256 + w * 64 + m) = q; }
    }
  __syncthreads();                                         // B9: lr ready
  {
    int src = lane & 3, mrow = w * 16 + (lane >> 2);
    float sp = HIFV(src * 64 + mrow), qp = HIFV(256 + src * 64 + mrow);
    sp = red4_add(sp); qp = red4_add(qp);
    if (src == 0){
      float mean = sp * (1.f / 128.f);
      float var  = qp * (1.f / 128.f) - mean * mean;
      HIFV(512 + 2 * mrow) = mean;
      HIFV(513 + 2 * mrow) = rsqrtf(var + 1e-5f);
    }
  }
  __syncthreads();                                         // B10: stats ready
  float* outBase = eOut + ((size_t)(b * N_ + i) * N_ + j0) * D_;
  #pragma unroll
  for (int ms = 0; ms < 4; ++ms)
    #pragma unroll
    for (int r = 0; r < 4; ++r){
      int m = ms * 16 + quad * 4 + r;
      float2 st = *(float2*)&HIFV(512 + 2 * m);
      float2 ov;
      ov.x = (acc4[0][ms][r] - st.x) * st.y * g1v[0] + bb1v[0];
      ov.y = (acc4[1][ms][r] - st.x) * st.y * g1v[1] + bb1v[1];
      *(float2*)&outBase[(size_t)m * D_ + w * 32 + c16 * 2] = ov;   // 128B line per row per instr
    }
#undef HIFV
}

extern "C" void kernel_launch(void* const* d_in, const int* in_sizes, int n_in,
                              void* d_out, int out_size, void* d_ws, size_t ws_size,
                              hipStream_t stream){
  const float* node   = (const float*)d_in[0];
  const float* edge   = (const float*)d_in[1];
  const float* wqkv_n = (const float*)d_in[3];
  const float* wqkv_e = (const float*)d_in[4];
  const float* lin0_w = (const float*)d_in[5];
  const float* lin0_b = (const float*)d_in[6];
  const float* ln0_g  = (const float*)d_in[7];
  const float* ln0_b  = (const float*)d_in[8];
  const float* ln1_g  = (const float*)d_in[9];
  const float* ln1_b  = (const float*)d_in[10];
  const float* nmlp_w1= (const float*)d_in[11];
  const float* nmlp_w2= (const float*)d_in[12];
  const float* nmlp_b2= (const float*)d_in[13];
  const float* e0_we  = (const float*)d_in[14];
  const float* e0_be  = (const float*)d_in[15];
  const float* e0_ws  = (const float*)d_in[16];
  const float* e0_bs  = (const float*)d_in[17];
  const float* e0_wt  = (const float*)d_in[18];
  const float* e0_bt  = (const float*)d_in[19];
  const float* e0_wer = (const float*)d_in[20];
  const float* e0_wec = (const float*)d_in[21];
  const float* e0_w1  = (const float*)d_in[22];
  const float* e0_b1  = (const float*)d_in[23];
  const float* e1_w1  = (const float*)d_in[24];
  const float* e1_w2  = (const float*)d_in[25];
  const float* e1_b2  = (const float*)d_in[26];
  const float* eln0_g = (const float*)d_in[27];
  const float* eln0_b = (const float*)d_in[28];
  const float* eln1_g = (const float*)d_in[29];
  const float* eln1_b = (const float*)d_in[30];

  unsigned short* E16   = (unsigned short*)d_ws;
  unsigned short* WqkvT = E16 + (size_t)EDGE_ELEMS;
  unsigned short* WeT   = WqkvT + 65536;
  unsigned short* W1T   = WeT + 32768;
  unsigned short* E1W1T = W1T + 16384;
  unsigned short* E1W2T = E1W1T + 32768;
  float* fbase  = (float*)(E1W2T + 32768);
  float* qkvn   = fbase;
  float* attn   = qkvn + (size_t)BN * 384;
  float* meanJ  = attn + NODE_ELEMS;
  float* meanI  = meanJ + NODE_ELEMS;
  float* rowAdd = meanI + NODE_ELEMS;
  float* colAdd = rowAdd + NODE_ELEMS;

  float* xOut = (float*)d_out;
  float* eOut = xOut + NODE_ELEMS;

  kprep<<<dim3(BN, 7), 384, 0, stream>>>(wqkv_e, e0_we, e0_w1, e1_w1, e1_w2,
                                         node, wqkv_n, edge,
                                         WqkvT, WeT, W1T, E1W1T, E1W2T,
                                         qkvn, E16, meanJ);
  kattnI<<<dim3(BN, 2), 256, 0, stream>>>(E16, WqkvT, qkvn, attn, meanI);
  knodeadd<<<BN / 2, 256, 0, stream>>>(node, attn, lin0_w, lin0_b, ln0_g, ln0_b,
                                       nmlp_w1, nmlp_w2, nmlp_b2, ln1_g, ln1_b,
                                       meanJ, meanI, e0_ws, e0_bs, e0_wt, e0_bt,
                                       e0_wer, e0_wec, e0_be,
                                       xOut, rowAdd, colAdd);
  kedge4<<<NN * B_ / 64, 256, 0, stream>>>(E16, WeT, W1T, E1W1T, E1W2T,
                                           rowAdd, colAdd, e0_b1,
                                           eln0_g, eln0_b, e1_b2, eln1_g, eln1_b,
                                           eOut);
}